// Round 1
// baseline (4674.415 us; speedup 1.0000x reference)
//
#include <hip/hip_runtime.h>

#define N_USERS 50000
#define NN0 200000
#define NN1 50000
#define NN2 12500
#define EE0 1600000
#define EE1 400000
#define EE2 100000
#define BQ 128

// ---------------- encoder projection: h128 = leaky([d|t|n|c]) ----------------
// 8 rows per thread (amortize W reads), 128 cols; wave0 of each 128-group = heavy cols.
__global__ __launch_bounds__(256) void k_proj(
    const float* __restrict__ xr,
    const float* __restrict__ Wd, const float* __restrict__ bd,
    const float* __restrict__ Wt, const float* __restrict__ bt,
    const float* __restrict__ Wn, const float* __restrict__ bn,
    const float* __restrict__ Wc, const float* __restrict__ bc,
    float* __restrict__ h128)
{
    int idx = blockIdx.x * 256 + threadIdx.x;
    int c = idx & 127;
    int rg = idx >> 7;
    if (rg >= N_USERS / 8) return;
    int r0 = rg * 8;
    const float* x = xr + (size_t)r0 * 1544;
    float acc[8];
    if (c < 64) {
        int off; const float* W; float b;
        if (c < 32) { off = 776; W = Wd + c; b = bd[c]; }
        else        { off = 6;   W = Wt + (c - 32); b = bt[c - 32]; }
        #pragma unroll
        for (int r = 0; r < 8; r++) acc[r] = b;
        const float* xp = x + off;
        #pragma unroll 4
        for (int k = 0; k < 768; k++) {
            float w = W[(size_t)k * 32];
            #pragma unroll
            for (int r = 0; r < 8; r++)
                acc[r] = fmaf(xp[(size_t)r * 1544 + k], w, acc[r]);
        }
    } else if (c < 96) {
        int j = c - 64;
        #pragma unroll
        for (int r = 0; r < 8; r++) {
            float a = bn[j];
            #pragma unroll
            for (int k = 0; k < 6; k++) a = fmaf(x[(size_t)r * 1544 + k], Wn[k * 32 + j], a);
            acc[r] = a;
        }
    } else {
        int j = c - 96;
        #pragma unroll
        for (int r = 0; r < 8; r++) {
            float a = bc[j];
            a = fmaf(x[(size_t)r * 1544 + 774], Wc[j], a);
            a = fmaf(x[(size_t)r * 1544 + 775], Wc[32 + j], a);
            acc[r] = a;
        }
    }
    #pragma unroll
    for (int r = 0; r < 8; r++) {
        float v = acc[r];
        v = v > 0.f ? v : 0.01f * v;
        h128[(size_t)(r0 + r) * 128 + c] = v;
    }
}

// ---------------- generic [n,128] @ [128,128] GEMM, optional row gather ------
// EPI 0: out = X@W ; EPI 1: out = prelu(X@W + bias)
template<int EPI>
__global__ __launch_bounds__(256) void k_gemm128(
    const float* __restrict__ X, const int* __restrict__ idx,
    const float* __restrict__ W, const float* __restrict__ bias,
    const float* __restrict__ pa, float* __restrict__ OUT, int n)
{
    __shared__ float xs[32][128];
    int base = blockIdx.x * 32;
    for (int i = threadIdx.x; i < 32 * 128; i += 256) {
        int r = i >> 7, c = i & 127;
        int row = base + r;
        float v = 0.f;
        if (row < n) {
            int srow = idx ? idx[row] : row;
            v = X[(size_t)srow * 128 + c];
        }
        xs[r][c] = v;
    }
    __syncthreads();
    int j = threadIdx.x & 127;
    int rh = (threadIdx.x >> 7) * 16;
    float acc[16];
    #pragma unroll
    for (int r = 0; r < 16; r++) acc[r] = 0.f;
    for (int k = 0; k < 128; k += 4) {
        float w0 = W[(size_t)(k + 0) * 128 + j];
        float w1 = W[(size_t)(k + 1) * 128 + j];
        float w2 = W[(size_t)(k + 2) * 128 + j];
        float w3 = W[(size_t)(k + 3) * 128 + j];
        #pragma unroll
        for (int r = 0; r < 16; r++) {
            float4 x4 = *(const float4*)(&xs[rh + r][k]);
            acc[r] = fmaf(x4.w, w3, fmaf(x4.z, w2, fmaf(x4.y, w1, fmaf(x4.x, w0, acc[r]))));
        }
    }
    #pragma unroll
    for (int r = 0; r < 16; r++) {
        int row = base + rh + r;
        if (row < n) {
            float v = acc[r];
            if (EPI == 1) { v += bias[j]; v = v > 0.f ? v : pa[j] * v; }
            OUT[(size_t)row * 128 + j] = v;
        }
    }
}

// ---------------- GCN helpers ------------------------------------------------
__global__ void k_fill(float* __restrict__ deg, int n) {
    int i = blockIdx.x * 256 + threadIdx.x;
    if (i < n) deg[i] = 1.0f;  // self loop
}

__global__ void k_count(const int* __restrict__ dst, float* __restrict__ deg, int E) {
    int e = blockIdx.x * 256 + threadIdx.x;
    if (e < E) unsafeAtomicAdd(&deg[dst[e]], 1.0f);
}

// dinv = rsqrt(deg); h *= dinv (in place); agg = h' (self-loop term pre-epilogue)
__global__ __launch_bounds__(256) void k_selfinit(
    float* __restrict__ h, const float* __restrict__ deg,
    float* __restrict__ dinv, float* __restrict__ agg, int n)
{
    size_t gid = (size_t)blockIdx.x * 256 + threadIdx.x;
    int i = (int)(gid >> 7);
    if (i >= n) return;
    int j = (int)(gid & 127);
    float r = rsqrtf(deg[i]);
    if (j == 0) dinv[i] = r;
    float v = h[(size_t)i * 128 + j] * r;
    h[(size_t)i * 128 + j] = v;
    agg[(size_t)i * 128 + j] = v;
}

// agg[dst] += h'[src]  (32 lanes per edge, float4 per lane)
__global__ __launch_bounds__(256) void k_agg(
    const float* __restrict__ h, const int* __restrict__ src,
    const int* __restrict__ dst, float* __restrict__ out, int E)
{
    size_t gid = (size_t)blockIdx.x * 256 + threadIdx.x;
    int e = (int)(gid >> 5);
    if (e >= E) return;
    int l = (int)(gid & 31);
    int s = src[e], d = dst[e];
    float4 v = ((const float4*)(h + (size_t)s * 128))[l];
    float* o = out + (size_t)d * 128 + (size_t)l * 4;
    unsafeAtomicAdd(o + 0, v.x);
    unsafeAtomicAdd(o + 1, v.y);
    unsafeAtomicAdd(o + 2, v.z);
    unsafeAtomicAdd(o + 3, v.w);
}

// y = relu(agg*dinv + b); POOL 0: store; 1: xnext[parent]+=y; 2: pooled[batch][256+j]+=y
template<int POOL>
__global__ __launch_bounds__(256) void k_brp(
    const float* __restrict__ agg, const float* __restrict__ dinv,
    const float* __restrict__ bias, const int* __restrict__ map,
    float* __restrict__ out, int n)
{
    size_t gid = (size_t)blockIdx.x * 256 + threadIdx.x;
    int i = (int)(gid >> 7);
    if (i >= n) return;
    int j = (int)(gid & 127);
    float v = agg[(size_t)i * 128 + j] * dinv[i] + bias[j];
    v = fmaxf(v, 0.f);
    if (POOL == 0) out[(size_t)i * 128 + j] = v;
    else if (POOL == 1) unsafeAtomicAdd(&out[(size_t)map[i] * 128 + j], v);
    else unsafeAtomicAdd(&out[(size_t)map[i] * 384 + 256 + j], v);
}

// pooled[batch[i]][coloff+j] += src[i][j]
__global__ __launch_bounds__(256) void k_bpool(
    const float* __restrict__ src, const int* __restrict__ bidx,
    float* __restrict__ pl, int coloff, int n)
{
    size_t gid = (size_t)blockIdx.x * 256 + threadIdx.x;
    int i = (int)(gid >> 7);
    if (i >= n) return;
    int j = (int)(gid & 127);
    unsafeAtomicAdd(&pl[(size_t)bidx[i] * 384 + coloff + j], src[(size_t)i * 128 + j]);
}

// small dense: out[r][j] = (relu?)(A[r,:K] @ W[:,j] + b[j]); grid 128 x 128
__global__ void k_mlp(const float* __restrict__ A, const float* __restrict__ W,
                      const float* __restrict__ b, float* __restrict__ out,
                      int K, int dorelu)
{
    __shared__ float as[384];
    int r = blockIdx.x, j = threadIdx.x;
    for (int i = j; i < K; i += 128) as[i] = A[(size_t)r * K + i];
    __syncthreads();
    float acc = b[j];
    for (int k = 0; k < K; k++) acc = fmaf(as[k], W[(size_t)k * 128 + j], acc);
    if (dorelu) acc = fmaxf(acc, 0.f);
    out[(size_t)r * 128 + j] = acc;
}

extern "C" void kernel_launch(void* const* d_in, const int* in_sizes, int n_in,
                              void* d_out, int out_size, void* d_ws, size_t ws_size,
                              hipStream_t stream)
{
    const float* x_raw  = (const float*)d_in[0];
    const float* W_des  = (const float*)d_in[1];
    const float* b_des  = (const float*)d_in[2];
    const float* W_twe  = (const float*)d_in[3];
    const float* b_twe  = (const float*)d_in[4];
    const float* W_num  = (const float*)d_in[5];
    const float* b_num  = (const float*)d_in[6];
    const float* W_cat  = (const float*)d_in[7];
    const float* b_cat  = (const float*)d_in[8];
    const float* W_in   = (const float*)d_in[9];
    const float* b_in   = (const float*)d_in[10];
    const float* prelua = (const float*)d_in[11];
    const float* W_conv = (const float*)d_in[12];
    const float* b_conv = (const float*)d_in[13];
    const float* Wc1    = (const float*)d_in[14];
    const float* bc1    = (const float*)d_in[15];
    const float* Wc2    = (const float*)d_in[16];
    const float* bc2    = (const float*)d_in[17];
    const int* nodelist = (const int*)d_in[18];
    const int* e0       = (const int*)d_in[19];
    const int* e1       = (const int*)d_in[20];
    const int* e2       = (const int*)d_in[21];
    const int* parent1  = (const int*)d_in[22];
    const int* parent2  = (const int*)d_in[23];
    const int* batch1   = (const int*)d_in[24];
    const int* batch2   = (const int*)d_in[25];

    // workspace layout (fp32), total ~265 MB
    float* ENC  = (float*)d_ws;                       // 50000*128  (h128, then enc in-place)
    float* H    = ENC  + (size_t)N_USERS * 128;       // 200000*128
    float* AGG  = H    + (size_t)NN0 * 128;           // 200000*128
    float* DEG  = AGG  + (size_t)NN0 * 128;           // 200000
    float* DINV = DEG  + NN0;                         // 200000
    float* X1   = DINV + NN0;                         // 50000*128
    float* X2   = X1   + (size_t)NN1 * 128;           // 12500*128
    float* PL   = X2   + (size_t)NN2 * 128;           // 128*384
    float* Z    = PL   + 128 * 384;                   // 128*128

    hipMemsetAsync(X1, 0, (size_t)NN1 * 128 * 4, stream);
    hipMemsetAsync(X2, 0, (size_t)NN2 * 128 * 4, stream);
    hipMemsetAsync(PL, 0, (size_t)128 * 384 * 4, stream);

    // encoder
    k_proj<<<(N_USERS / 8) * 128 / 256, 256, 0, stream>>>(
        x_raw, W_des, b_des, W_twe, b_twe, W_num, b_num, W_cat, b_cat, ENC);
    k_gemm128<1><<<(N_USERS + 31) / 32, 256, 0, stream>>>(
        ENC, nullptr, W_in, b_in, prelua, ENC, N_USERS);

    // ---- layer 0 (N0 nodes, E0 edges), pool -> X1 via parent1
    k_fill<<<(NN0 + 255) / 256, 256, 0, stream>>>(DEG, NN0);
    k_count<<<(EE0 + 255) / 256, 256, 0, stream>>>(e0 + EE0, DEG, EE0);
    k_gemm128<0><<<(NN0 + 31) / 32, 256, 0, stream>>>(
        ENC, nodelist, W_conv, nullptr, nullptr, H, NN0);
    k_selfinit<<<(int)(((size_t)NN0 * 128 + 255) / 256), 256, 0, stream>>>(H, DEG, DINV, AGG, NN0);
    k_agg<<<(int)(((size_t)EE0 * 32 + 255) / 256), 256, 0, stream>>>(H, e0, e0 + EE0, AGG, EE0);
    k_brp<1><<<(int)(((size_t)NN0 * 128 + 255) / 256), 256, 0, stream>>>(
        AGG, DINV, b_conv, parent1, X1, NN0);

    // ---- layer 1 (N1 nodes, E1 edges), pool -> X2 via parent2
    k_fill<<<(NN1 + 255) / 256, 256, 0, stream>>>(DEG, NN1);
    k_count<<<(EE1 + 255) / 256, 256, 0, stream>>>(e1 + EE1, DEG, EE1);
    k_gemm128<0><<<(NN1 + 31) / 32, 256, 0, stream>>>(
        X1, nullptr, W_conv + 16384, nullptr, nullptr, H, NN1);
    k_selfinit<<<(int)(((size_t)NN1 * 128 + 255) / 256), 256, 0, stream>>>(H, DEG, DINV, AGG, NN1);
    k_agg<<<(int)(((size_t)EE1 * 32 + 255) / 256), 256, 0, stream>>>(H, e1, e1 + EE1, AGG, EE1);
    k_brp<1><<<(int)(((size_t)NN1 * 128 + 255) / 256), 256, 0, stream>>>(
        AGG, DINV, b_conv + 128, parent2, X2, NN1);

    // ---- layer 2 (N2 nodes, E2 edges), fused batch-pool of y2 into PL[:,256:384]
    k_fill<<<(NN2 + 255) / 256, 256, 0, stream>>>(DEG, NN2);
    k_count<<<(EE2 + 255) / 256, 256, 0, stream>>>(e2 + EE2, DEG, EE2);
    k_gemm128<0><<<(NN2 + 31) / 32, 256, 0, stream>>>(
        X2, nullptr, W_conv + 32768, nullptr, nullptr, H, NN2);
    k_selfinit<<<(int)(((size_t)NN2 * 128 + 255) / 256), 256, 0, stream>>>(H, DEG, DINV, AGG, NN2);
    k_agg<<<(int)(((size_t)EE2 * 32 + 255) / 256), 256, 0, stream>>>(H, e2, e2 + EE2, AGG, EE2);
    k_brp<2><<<(int)(((size_t)NN2 * 128 + 255) / 256), 256, 0, stream>>>(
        AGG, DINV, b_conv + 256, batch2, PL, NN2);

    // batch pooling parts 0 and 1
    k_bpool<<<(int)(((size_t)NN1 * 128 + 255) / 256), 256, 0, stream>>>(X1, batch1, PL, 0, NN1);
    k_bpool<<<(int)(((size_t)NN2 * 128 + 255) / 256), 256, 0, stream>>>(X2, batch2, PL, 128, NN2);

    // final MLP
    k_mlp<<<128, 128, 0, stream>>>(PL, Wc1, bc1, Z, 384, 1);
    k_mlp<<<128, 128, 0, stream>>>(Z, Wc2, bc2, (float*)d_out, 128, 0);
}

// Round 2
// 1466.922 us; speedup vs baseline: 3.1865x; 3.1865x over previous
//
#include <hip/hip_runtime.h>

#define N_USERS 50000
#define NN0 200000
#define NN1 50000
#define NN2 12500
#define EE0 1600000
#define EE1 400000
#define EE2 100000

// ---------------- encoder projection: h128 = leaky([d|t|n|c]) ----------------
__global__ __launch_bounds__(256) void k_proj(
    const float* __restrict__ xr,
    const float* __restrict__ Wd, const float* __restrict__ bd,
    const float* __restrict__ Wt, const float* __restrict__ bt,
    const float* __restrict__ Wn, const float* __restrict__ bn,
    const float* __restrict__ Wc, const float* __restrict__ bc,
    float* __restrict__ h128)
{
    int idx = blockIdx.x * 256 + threadIdx.x;
    int c = idx & 127;
    int rg = idx >> 7;
    if (rg >= N_USERS / 8) return;
    int r0 = rg * 8;
    const float* x = xr + (size_t)r0 * 1544;
    float acc[8];
    if (c < 64) {
        int off; const float* W; float b;
        if (c < 32) { off = 776; W = Wd + c; b = bd[c]; }
        else        { off = 6;   W = Wt + (c - 32); b = bt[c - 32]; }
        #pragma unroll
        for (int r = 0; r < 8; r++) acc[r] = b;
        const float* xp = x + off;
        #pragma unroll 4
        for (int k = 0; k < 768; k++) {
            float w = W[(size_t)k * 32];
            #pragma unroll
            for (int r = 0; r < 8; r++)
                acc[r] = fmaf(xp[(size_t)r * 1544 + k], w, acc[r]);
        }
    } else if (c < 96) {
        int j = c - 64;
        #pragma unroll
        for (int r = 0; r < 8; r++) {
            float a = bn[j];
            #pragma unroll
            for (int k = 0; k < 6; k++) a = fmaf(x[(size_t)r * 1544 + k], Wn[k * 32 + j], a);
            acc[r] = a;
        }
    } else {
        int j = c - 96;
        #pragma unroll
        for (int r = 0; r < 8; r++) {
            float a = bc[j];
            a = fmaf(x[(size_t)r * 1544 + 774], Wc[j], a);
            a = fmaf(x[(size_t)r * 1544 + 775], Wc[32 + j], a);
            acc[r] = a;
        }
    }
    #pragma unroll
    for (int r = 0; r < 8; r++) {
        float v = acc[r];
        v = v > 0.f ? v : 0.01f * v;
        h128[(size_t)(r0 + r) * 128 + c] = v;
    }
}

// ---------------- [n,128] @ [128,128] GEMM, optional row gather --------------
template<int EPI> // 0: plain, 1: prelu(x+b)
__global__ __launch_bounds__(256) void k_gemm128(
    const float* __restrict__ X, const int* __restrict__ idx,
    const float* __restrict__ W, const float* __restrict__ bias,
    const float* __restrict__ pa, float* __restrict__ OUT, int n)
{
    __shared__ float xs[32][128];
    int base = blockIdx.x * 32;
    for (int i = threadIdx.x; i < 32 * 128; i += 256) {
        int r = i >> 7, c = i & 127;
        int row = base + r;
        float v = 0.f;
        if (row < n) {
            int srow = idx ? idx[row] : row;
            v = X[(size_t)srow * 128 + c];
        }
        xs[r][c] = v;
    }
    __syncthreads();
    int j = threadIdx.x & 127;
    int rh = (threadIdx.x >> 7) * 16;
    float acc[16];
    #pragma unroll
    for (int r = 0; r < 16; r++) acc[r] = 0.f;
    for (int k = 0; k < 128; k += 4) {
        float w0 = W[(size_t)(k + 0) * 128 + j];
        float w1 = W[(size_t)(k + 1) * 128 + j];
        float w2 = W[(size_t)(k + 2) * 128 + j];
        float w3 = W[(size_t)(k + 3) * 128 + j];
        #pragma unroll
        for (int r = 0; r < 16; r++) {
            float4 x4 = *(const float4*)(&xs[rh + r][k]);
            acc[r] = fmaf(x4.w, w3, fmaf(x4.z, w2, fmaf(x4.y, w1, fmaf(x4.x, w0, acc[r]))));
        }
    }
    #pragma unroll
    for (int r = 0; r < 16; r++) {
        int row = base + rh + r;
        if (row < n) {
            float v = acc[r];
            if (EPI == 1) { v += bias[j]; v = v > 0.f ? v : pa[j] * v; }
            OUT[(size_t)row * 128 + j] = v;
        }
    }
}

// ---------------- CSR build: count -> scan -> scatter ------------------------
__global__ void k_count_int(const int* __restrict__ key, int* __restrict__ deg, int E) {
    int e = blockIdx.x * 256 + threadIdx.x;
    if (e < E) atomicAdd(&deg[key[e]], 1);
}

// block scans 1024 elements (4/thread), writes exclusive partials + block sum
__global__ __launch_bounds__(256) void k_scan_block(
    const int* __restrict__ in, int* __restrict__ out, int* __restrict__ bsum, int n)
{
    __shared__ int sh[256];
    int t = threadIdx.x;
    int base = blockIdx.x * 1024 + t * 4;
    int v[4], s = 0;
    #pragma unroll
    for (int k = 0; k < 4; k++) { v[k] = (base + k < n) ? in[base + k] : 0; s += v[k]; }
    sh[t] = s;
    __syncthreads();
    for (int off = 1; off < 256; off <<= 1) {
        int x = 0;
        if (t >= off) x = sh[t - off];
        __syncthreads();
        if (t >= off) sh[t] += x;
        __syncthreads();
    }
    int ex = sh[t] - s;
    if (t == 255) bsum[blockIdx.x] = sh[255];
    #pragma unroll
    for (int k = 0; k < 4; k++) {
        if (base + k < n) out[base + k] = ex;
        ex += v[k];
    }
}

__global__ __launch_bounds__(256) void k_scan_top(int* __restrict__ bsum, int nb) {
    __shared__ int sh[256];
    int t = threadIdx.x;
    int v = (t < nb) ? bsum[t] : 0;
    sh[t] = v;
    __syncthreads();
    for (int off = 1; off < 256; off <<= 1) {
        int x = 0;
        if (t >= off) x = sh[t - off];
        __syncthreads();
        if (t >= off) sh[t] += x;
        __syncthreads();
    }
    if (t < nb) bsum[t] = sh[t] - v; // exclusive
}

__global__ __launch_bounds__(256) void k_scan_add(
    int* __restrict__ out, int* __restrict__ curs, const int* __restrict__ bsum,
    int n, int E)
{
    int t = threadIdx.x;
    int base = blockIdx.x * 1024 + t * 4;
    int add = bsum[blockIdx.x];
    #pragma unroll
    for (int k = 0; k < 4; k++) {
        int i = base + k;
        if (i < n) { int r = out[i] + add; out[i] = r; curs[i] = r; }
    }
    if (blockIdx.x == 0 && t == 0) out[n] = E;
}

__global__ void k_scatter(const int* __restrict__ val, const int* __restrict__ key,
                          int* __restrict__ curs, int* __restrict__ elist, int E) {
    int e = blockIdx.x * 256 + threadIdx.x;
    if (e < E) { int p = atomicAdd(&curs[key[e]], 1); elist[p] = val[e]; }
}

__global__ void k_scatter_iota(const int* __restrict__ key, int* __restrict__ curs,
                               int* __restrict__ elist, int E) {
    int e = blockIdx.x * 256 + threadIdx.x;
    if (e < E) { int p = atomicAdd(&curs[key[e]], 1); elist[p] = e; }
}

// ---------------- GCN pieces -------------------------------------------------
__global__ void k_dinv(const int* __restrict__ ideg, float* __restrict__ dinv, int n) {
    int i = blockIdx.x * 256 + threadIdx.x;
    if (i < n) dinv[i] = rsqrtf((float)(ideg[i] + 1)); // +1 self loop
}

// h *= dinv[row] in place (produces h')
__global__ __launch_bounds__(256) void k_selfscale(
    float* __restrict__ h, const float* __restrict__ dinv, int n)
{
    size_t gid = (size_t)blockIdx.x * 256 + threadIdx.x;
    int i = (int)(gid >> 7);
    if (i >= n) return;
    int j = (int)(gid & 127);
    h[(size_t)i * 128 + j] *= dinv[i];
}

// out[d] = relu((h'[d] + sum_{src in N(d)} h'[src]) * dinv[d] + bias)
__global__ __launch_bounds__(256) void k_gather(
    const float* __restrict__ h, const int* __restrict__ rowst,
    const int* __restrict__ elist, const float* __restrict__ dinv,
    const float* __restrict__ bias, float* __restrict__ out, int n)
{
    size_t gid = (size_t)blockIdx.x * 256 + threadIdx.x;
    int d = (int)(gid >> 5);
    if (d >= n) return;
    int l = (int)(gid & 31);
    const float4* hv = (const float4*)h;
    float4 acc = hv[(size_t)d * 32 + l]; // self loop
    int s0 = rowst[d], s1 = rowst[d + 1];
    for (int e = s0; e < s1; ++e) {
        int s = elist[e];
        float4 v = hv[(size_t)s * 32 + l];
        acc.x += v.x; acc.y += v.y; acc.z += v.z; acc.w += v.w;
    }
    float dv = dinv[d];
    const float4 b = ((const float4*)bias)[l];
    float4 y;
    y.x = fmaxf(fmaf(acc.x, dv, b.x), 0.f);
    y.y = fmaxf(fmaf(acc.y, dv, b.y), 0.f);
    y.z = fmaxf(fmaf(acc.z, dv, b.z), 0.f);
    y.w = fmaxf(fmaf(acc.w, dv, b.w), 0.f);
    ((float4*)out)[(size_t)d * 32 + l] = y;
}

// out[p] = relu(sum_{i in children(p)} Y[i])
__global__ __launch_bounds__(256) void k_poolgather(
    const float* __restrict__ Y, const int* __restrict__ rowst,
    const int* __restrict__ elist, float* __restrict__ out, int np)
{
    size_t gid = (size_t)blockIdx.x * 256 + threadIdx.x;
    int p = (int)(gid >> 5);
    if (p >= np) return;
    int l = (int)(gid & 31);
    const float4* yv = (const float4*)Y;
    float4 acc = {0.f, 0.f, 0.f, 0.f};
    int s0 = rowst[p], s1 = rowst[p + 1];
    for (int e = s0; e < s1; ++e) {
        int i = elist[e];
        float4 v = yv[(size_t)i * 32 + l];
        acc.x += v.x; acc.y += v.y; acc.z += v.z; acc.w += v.w;
    }
    float4 y;
    y.x = fmaxf(acc.x, 0.f); y.y = fmaxf(acc.y, 0.f);
    y.z = fmaxf(acc.z, 0.f); y.w = fmaxf(acc.w, 0.f);
    ((float4*)out)[(size_t)p * 32 + l] = y;
}

// sorted-key segmented sum: pl[bidx[r]][coloff+j] += src[r][j], few boundary atomics
__global__ __launch_bounds__(128) void k_bpool_sorted(
    const float* __restrict__ src, const int* __restrict__ bidx,
    float* __restrict__ pl, int coloff, int n)
{
    int j = threadIdx.x;
    int r0 = blockIdx.x * 128;
    if (r0 >= n) return;
    int r1 = min(r0 + 128, n);
    float acc = 0.f;
    int prev = bidx[r0];
    for (int r = r0; r < r1; ++r) {
        int b = bidx[r];
        if (b != prev) {
            unsafeAtomicAdd(&pl[(size_t)prev * 384 + coloff + j], acc);
            acc = 0.f; prev = b;
        }
        acc += src[(size_t)r * 128 + j];
    }
    unsafeAtomicAdd(&pl[(size_t)prev * 384 + coloff + j], acc);
}

// small dense MLP: out[r][j] = (relu?)(A[r,:K] @ W[:,j] + b[j])
__global__ void k_mlp(const float* __restrict__ A, const float* __restrict__ W,
                      const float* __restrict__ b, float* __restrict__ out,
                      int K, int dorelu)
{
    __shared__ float as[384];
    int r = blockIdx.x, j = threadIdx.x;
    for (int i = j; i < K; i += 128) as[i] = A[(size_t)r * K + i];
    __syncthreads();
    float acc = b[j];
    for (int k = 0; k < K; k++) acc = fmaf(as[k], W[(size_t)k * 128 + j], acc);
    if (dorelu) acc = fmaxf(acc, 0.f);
    out[(size_t)r * 128 + j] = acc;
}

// ---------------- host-side helpers ------------------------------------------
static void build_csr(const int* key, const int* val, int E, int n,
                      int* ideg, int* rowst, int* curs, int* elist, int* bsum,
                      hipStream_t stream)
{
    hipMemsetAsync(ideg, 0, (size_t)n * 4, stream);
    k_count_int<<<(E + 255) / 256, 256, 0, stream>>>(key, ideg, E);
    int nb = (n + 1023) / 1024;
    k_scan_block<<<nb, 256, 0, stream>>>(ideg, rowst, bsum, n);
    k_scan_top<<<1, 256, 0, stream>>>(bsum, nb);
    k_scan_add<<<nb, 256, 0, stream>>>(rowst, curs, bsum, n, E);
    if (val) k_scatter<<<(E + 255) / 256, 256, 0, stream>>>(val, key, curs, elist, E);
    else     k_scatter_iota<<<(E + 255) / 256, 256, 0, stream>>>(key, curs, elist, E);
}

extern "C" void kernel_launch(void* const* d_in, const int* in_sizes, int n_in,
                              void* d_out, int out_size, void* d_ws, size_t ws_size,
                              hipStream_t stream)
{
    const float* x_raw  = (const float*)d_in[0];
    const float* W_des  = (const float*)d_in[1];
    const float* b_des  = (const float*)d_in[2];
    const float* W_twe  = (const float*)d_in[3];
    const float* b_twe  = (const float*)d_in[4];
    const float* W_num  = (const float*)d_in[5];
    const float* b_num  = (const float*)d_in[6];
    const float* W_cat  = (const float*)d_in[7];
    const float* b_cat  = (const float*)d_in[8];
    const float* W_in   = (const float*)d_in[9];
    const float* b_in   = (const float*)d_in[10];
    const float* prelua = (const float*)d_in[11];
    const float* W_conv = (const float*)d_in[12];
    const float* b_conv = (const float*)d_in[13];
    const float* Wc1    = (const float*)d_in[14];
    const float* bc1    = (const float*)d_in[15];
    const float* Wc2    = (const float*)d_in[16];
    const float* bc2    = (const float*)d_in[17];
    const int* nodelist = (const int*)d_in[18];
    const int* e0       = (const int*)d_in[19];
    const int* e1       = (const int*)d_in[20];
    const int* e2       = (const int*)d_in[21];
    const int* parent1  = (const int*)d_in[22];
    const int* parent2  = (const int*)d_in[23];
    const int* batch1   = (const int*)d_in[24];
    const int* batch2   = (const int*)d_in[25];

    // ---- workspace layout (~263 MB) ----
    float* ENC = (float*)d_ws;                 // 50000*128 (dead after L0 gemm)
    // CSR scratch aliases ENC region (only used after ENC is dead):
    int* ELIST = (int*)d_ws;                   // 1.6M
    int* ROWST = ELIST + 1600000;              // 200001
    int* CURS  = ROWST + 200001;               // 200000
    int* IDEG  = CURS  + 200000;               // 200000
    int* BSUM  = IDEG  + 200000;               // 256
    float* H    = ENC + (size_t)N_USERS * 128; // 200000*128
    float* Y    = H   + (size_t)NN0 * 128;     // 200000*128
    float* DINV = Y   + (size_t)NN0 * 128;     // 200000
    float* X1   = DINV + NN0;                  // 50000*128
    float* X2   = X1  + (size_t)NN1 * 128;     // 12500*128
    float* PL   = X2  + (size_t)NN2 * 128;     // 128*384
    float* Z    = PL  + 128 * 384;             // 128*128

    hipMemsetAsync(PL, 0, (size_t)128 * 384 * 4, stream);

    // ---- encoder (ENC live) ----
    k_proj<<<(N_USERS / 8) * 128 / 256, 256, 0, stream>>>(
        x_raw, W_des, b_des, W_twe, b_twe, W_num, b_num, W_cat, b_cat, ENC);
    k_gemm128<1><<<(N_USERS + 31) / 32, 256, 0, stream>>>(
        ENC, nullptr, W_in, b_in, prelua, ENC, N_USERS);

    // ---- layer 0 ----
    k_gemm128<0><<<(NN0 + 31) / 32, 256, 0, stream>>>(
        ENC, nodelist, W_conv, nullptr, nullptr, H, NN0);           // ENC dead after this
    build_csr(e0 + EE0, e0, EE0, NN0, IDEG, ROWST, CURS, ELIST, BSUM, stream);
    k_dinv<<<(NN0 + 255) / 256, 256, 0, stream>>>(IDEG, DINV, NN0);
    k_selfscale<<<(int)(((size_t)NN0 * 128 + 255) / 256), 256, 0, stream>>>(H, DINV, NN0);
    k_gather<<<(int)(((size_t)NN0 * 32 + 255) / 256), 256, 0, stream>>>(
        H, ROWST, ELIST, DINV, b_conv, Y, NN0);
    build_csr(parent1, nullptr, NN0, NN1, IDEG, ROWST, CURS, ELIST, BSUM, stream);
    k_poolgather<<<(int)(((size_t)NN1 * 32 + 255) / 256), 256, 0, stream>>>(
        Y, ROWST, ELIST, X1, NN1);

    // ---- layer 1 ----
    k_gemm128<0><<<(NN1 + 31) / 32, 256, 0, stream>>>(
        X1, nullptr, W_conv + 16384, nullptr, nullptr, H, NN1);
    build_csr(e1 + EE1, e1, EE1, NN1, IDEG, ROWST, CURS, ELIST, BSUM, stream);
    k_dinv<<<(NN1 + 255) / 256, 256, 0, stream>>>(IDEG, DINV, NN1);
    k_selfscale<<<(int)(((size_t)NN1 * 128 + 255) / 256), 256, 0, stream>>>(H, DINV, NN1);
    k_gather<<<(int)(((size_t)NN1 * 32 + 255) / 256), 256, 0, stream>>>(
        H, ROWST, ELIST, DINV, b_conv + 128, Y, NN1);
    build_csr(parent2, nullptr, NN1, NN2, IDEG, ROWST, CURS, ELIST, BSUM, stream);
    k_poolgather<<<(int)(((size_t)NN2 * 32 + 255) / 256), 256, 0, stream>>>(
        Y, ROWST, ELIST, X2, NN2);

    // ---- layer 2 ----
    k_gemm128<0><<<(NN2 + 31) / 32, 256, 0, stream>>>(
        X2, nullptr, W_conv + 32768, nullptr, nullptr, H, NN2);
    build_csr(e2 + EE2, e2, EE2, NN2, IDEG, ROWST, CURS, ELIST, BSUM, stream);
    k_dinv<<<(NN2 + 255) / 256, 256, 0, stream>>>(IDEG, DINV, NN2);
    k_selfscale<<<(int)(((size_t)NN2 * 128 + 255) / 256), 256, 0, stream>>>(H, DINV, NN2);
    k_gather<<<(int)(((size_t)NN2 * 32 + 255) / 256), 256, 0, stream>>>(
        H, ROWST, ELIST, DINV, b_conv + 256, Y, NN2);

    // ---- batch pooling (sorted keys -> segmented, few atomics) ----
    k_bpool_sorted<<<(NN1 + 127) / 128, 128, 0, stream>>>(X1, batch1, PL, 0, NN1);
    k_bpool_sorted<<<(NN2 + 127) / 128, 128, 0, stream>>>(X2, batch2, PL, 128, NN2);
    k_bpool_sorted<<<(NN2 + 127) / 128, 128, 0, stream>>>(Y,  batch2, PL, 256, NN2);

    // ---- final MLP ----
    k_mlp<<<128, 128, 0, stream>>>(PL, Wc1, bc1, Z, 384, 1);
    k_mlp<<<128, 128, 0, stream>>>(Z, Wc2, bc2, (float*)d_out, 128, 0);
}

// Round 3
// 1145.445 us; speedup vs baseline: 4.0809x; 1.2807x over previous
//
#include <hip/hip_runtime.h>

#define N_USERS 50000
#define NN0 200000
#define NN1 50000
#define NN2 12500
#define EE0 1600000
#define EE1 400000
#define EE2 100000

// ---------------- encoder: h128[r][0:32|32:64|64:96|96:128] = leaky(d|t|n|c) --
// 64 rows x 128 cols per block, BK=32 LDS-tiled over the two 768-wide slices.
__global__ __launch_bounds__(256) void k_enc(
    const float* __restrict__ xr,
    const float* __restrict__ Wd, const float* __restrict__ bd,
    const float* __restrict__ Wt, const float* __restrict__ bt,
    const float* __restrict__ Wn, const float* __restrict__ bn,
    const float* __restrict__ Wc, const float* __restrict__ bc,
    float* __restrict__ h128)
{
    __shared__ float Xs[2][64][36];  // [des|tweet][row][k] pad->16B-aligned cols
    __shared__ float Ws[32][64];     // [k][col] col<32: des, else tweet
    __shared__ float xnc[64][8];     // cols 0..5 (num), 774..775 (cat)

    int t = threadIdx.x;
    int tx = t & 15, ty = t >> 4;
    int base = blockIdx.x * 64;
    int gc = tx * 4;

    // stage num/cat inputs once
    if (t < 64) {
        int row = base + t;
        if (row < N_USERS) {
            const float* xp = xr + (size_t)row * 1544;
            float4 a = *(const float4*)xp;
            float2 b2 = *(const float2*)(xp + 4);
            float2 c2 = *(const float2*)(xp + 774);
            xnc[t][0] = a.x; xnc[t][1] = a.y; xnc[t][2] = a.z; xnc[t][3] = a.w;
            xnc[t][4] = b2.x; xnc[t][5] = b2.y; xnc[t][6] = c2.x; xnc[t][7] = c2.y;
        } else {
            #pragma unroll
            for (int k = 0; k < 8; k++) xnc[t][k] = 0.f;
        }
    }

    float acc[4][4];
    #pragma unroll
    for (int r = 0; r < 4; r++)
        #pragma unroll
        for (int c = 0; c < 4; c++) acc[r][c] = 0.f;

    int srow = base + (t >> 2);
    int q = t & 3;
    bool vrow = srow < N_USERS;
    const float* xrow = xr + (size_t)srow * 1544;

    for (int kc = 0; kc < 768; kc += 32) {
        __syncthreads();
        // stage X chunks: 4 threads/row, 8 cols each, float2 (offset 6 is only 8B-aligned)
        {
            int col = q * 8;
            #pragma unroll
            for (int i = 0; i < 4; i++) {
                float2 vd = {0.f, 0.f}, vt = {0.f, 0.f};
                if (vrow) {
                    vd = *(const float2*)(xrow + 776 + kc + col + 2 * i);
                    vt = *(const float2*)(xrow + 6   + kc + col + 2 * i);
                }
                Xs[0][t >> 2][col + 2 * i] = vd.x; Xs[0][t >> 2][col + 2 * i + 1] = vd.y;
                Xs[1][t >> 2][col + 2 * i] = vt.x; Xs[1][t >> 2][col + 2 * i + 1] = vt.y;
            }
        }
        // stage W chunk [32][64]
        #pragma unroll
        for (int h = 0; h < 2; h++) {
            int idx = t * 8 + h * 4;
            int row = idx >> 6, col = idx & 63;
            float4 w = (col < 32) ? *(const float4*)(Wd + (size_t)(kc + row) * 32 + col)
                                  : *(const float4*)(Wt + (size_t)(kc + row) * 32 + col - 32);
            *(float4*)&Ws[row][col] = w;
        }
        __syncthreads();

        int plane = (tx < 8) ? 0 : 1;
        #pragma unroll
        for (int k = 0; k < 32; k += 4) {
            float4 w0 = *(const float4*)&Ws[k + 0][gc];
            float4 w1 = *(const float4*)&Ws[k + 1][gc];
            float4 w2 = *(const float4*)&Ws[k + 2][gc];
            float4 w3 = *(const float4*)&Ws[k + 3][gc];
            #pragma unroll
            for (int r = 0; r < 4; r++) {
                float4 xv = *(const float4*)&Xs[plane][ty * 4 + r][k];
                acc[r][0] = fmaf(xv.x, w0.x, fmaf(xv.y, w1.x, fmaf(xv.z, w2.x, fmaf(xv.w, w3.x, acc[r][0]))));
                acc[r][1] = fmaf(xv.x, w0.y, fmaf(xv.y, w1.y, fmaf(xv.z, w2.y, fmaf(xv.w, w3.y, acc[r][1]))));
                acc[r][2] = fmaf(xv.x, w0.z, fmaf(xv.y, w1.z, fmaf(xv.z, w2.z, fmaf(xv.w, w3.z, acc[r][2]))));
                acc[r][3] = fmaf(xv.x, w0.w, fmaf(xv.y, w1.w, fmaf(xv.z, w2.w, fmaf(xv.w, w3.w, acc[r][3]))));
            }
        }
    }

    // epilogue: bias + leaky, plus light cols (num/cat) from xnc
    #pragma unroll
    for (int r = 0; r < 4; r++) {
        int lr = ty * 4 + r;
        int row = base + lr;
        if (row >= N_USERS) continue;
        // heavy
        float4 hv;
        float* pa = &hv.x;
        #pragma unroll
        for (int c = 0; c < 4; c++) {
            int j = gc + c;
            float v = acc[r][c] + ((j < 32) ? bd[j] : bt[j - 32]);
            pa[c] = v > 0.f ? v : 0.01f * v;
        }
        *(float4*)(h128 + (size_t)row * 128 + gc) = hv;
        // light
        float4 lv;
        float* pl = &lv.x;
        #pragma unroll
        for (int c = 0; c < 4; c++) {
            float v;
            if (tx < 8) { // num, j = gc+c
                int j = gc + c;
                v = bn[j];
                #pragma unroll
                for (int k = 0; k < 6; k++) v = fmaf(xnc[lr][k], Wn[k * 32 + j], v);
            } else {      // cat, j = gc-32+c
                int j = gc - 32 + c;
                v = bc[j];
                v = fmaf(xnc[lr][6], Wc[j], v);
                v = fmaf(xnc[lr][7], Wc[32 + j], v);
            }
            pl[c] = v > 0.f ? v : 0.01f * v;
        }
        *(float4*)(h128 + (size_t)row * 128 + 64 + gc) = lv;
    }
}

// ---------------- [n,128] @ [128,128] GEMM, optional row gather --------------
template<int EPI> // 0: plain, 1: prelu(x+b)
__global__ __launch_bounds__(256) void k_gemm128(
    const float* __restrict__ X, const int* __restrict__ idx,
    const float* __restrict__ W, const float* __restrict__ bias,
    const float* __restrict__ pa, float* __restrict__ OUT, int n)
{
    __shared__ float xs[32][128];
    int base = blockIdx.x * 32;
    for (int i = threadIdx.x; i < 32 * 128; i += 256) {
        int r = i >> 7, c = i & 127;
        int row = base + r;
        float v = 0.f;
        if (row < n) {
            int srow = idx ? idx[row] : row;
            v = X[(size_t)srow * 128 + c];
        }
        xs[r][c] = v;
    }
    __syncthreads();
    int j = threadIdx.x & 127;
    int rh = (threadIdx.x >> 7) * 16;
    float acc[16];
    #pragma unroll
    for (int r = 0; r < 16; r++) acc[r] = 0.f;
    for (int k = 0; k < 128; k += 4) {
        float w0 = W[(size_t)(k + 0) * 128 + j];
        float w1 = W[(size_t)(k + 1) * 128 + j];
        float w2 = W[(size_t)(k + 2) * 128 + j];
        float w3 = W[(size_t)(k + 3) * 128 + j];
        #pragma unroll
        for (int r = 0; r < 16; r++) {
            float4 x4 = *(const float4*)(&xs[rh + r][k]);
            acc[r] = fmaf(x4.w, w3, fmaf(x4.z, w2, fmaf(x4.y, w1, fmaf(x4.x, w0, acc[r]))));
        }
    }
    #pragma unroll
    for (int r = 0; r < 16; r++) {
        int row = base + rh + r;
        if (row < n) {
            float v = acc[r];
            if (EPI == 1) { v += bias[j]; v = v > 0.f ? v : pa[j] * v; }
            OUT[(size_t)row * 128 + j] = v;
        }
    }
}

// ---------------- CSR build: count -> scan -> scatter ------------------------
__global__ void k_count_int(const int* __restrict__ key, int* __restrict__ deg, int E) {
    int e = blockIdx.x * 256 + threadIdx.x;
    if (e < E) atomicAdd(&deg[key[e]], 1);
}

__global__ __launch_bounds__(256) void k_scan_block(
    const int* __restrict__ in, int* __restrict__ out, int* __restrict__ bsum, int n)
{
    __shared__ int sh[256];
    int t = threadIdx.x;
    int base = blockIdx.x * 1024 + t * 4;
    int v[4], s = 0;
    #pragma unroll
    for (int k = 0; k < 4; k++) { v[k] = (base + k < n) ? in[base + k] : 0; s += v[k]; }
    sh[t] = s;
    __syncthreads();
    for (int off = 1; off < 256; off <<= 1) {
        int x = 0;
        if (t >= off) x = sh[t - off];
        __syncthreads();
        if (t >= off) sh[t] += x;
        __syncthreads();
    }
    int ex = sh[t] - s;
    if (t == 255) bsum[blockIdx.x] = sh[255];
    #pragma unroll
    for (int k = 0; k < 4; k++) {
        if (base + k < n) out[base + k] = ex;
        ex += v[k];
    }
}

__global__ __launch_bounds__(256) void k_scan_top(int* __restrict__ bsum, int nb) {
    __shared__ int sh[256];
    int t = threadIdx.x;
    int v = (t < nb) ? bsum[t] : 0;
    sh[t] = v;
    __syncthreads();
    for (int off = 1; off < 256; off <<= 1) {
        int x = 0;
        if (t >= off) x = sh[t - off];
        __syncthreads();
        if (t >= off) sh[t] += x;
        __syncthreads();
    }
    if (t < nb) bsum[t] = sh[t] - v; // exclusive
}

__global__ __launch_bounds__(256) void k_scan_add(
    int* __restrict__ out, int* __restrict__ curs, const int* __restrict__ bsum,
    int n, int E)
{
    int t = threadIdx.x;
    int base = blockIdx.x * 1024 + t * 4;
    int add = bsum[blockIdx.x];
    #pragma unroll
    for (int k = 0; k < 4; k++) {
        int i = base + k;
        if (i < n) { int r = out[i] + add; out[i] = r; curs[i] = r; }
    }
    if (blockIdx.x == 0 && t == 0) out[n] = E;
}

__global__ void k_scatter(const int* __restrict__ val, const int* __restrict__ key,
                          int* __restrict__ curs, int* __restrict__ elist, int E) {
    int e = blockIdx.x * 256 + threadIdx.x;
    if (e < E) { int p = atomicAdd(&curs[key[e]], 1); elist[p] = val[e]; }
}

__global__ void k_scatter_iota(const int* __restrict__ key, int* __restrict__ curs,
                               int* __restrict__ elist, int E) {
    int e = blockIdx.x * 256 + threadIdx.x;
    if (e < E) { int p = atomicAdd(&curs[key[e]], 1); elist[p] = e; }
}

// ---------------- GCN pieces -------------------------------------------------
__global__ void k_dinv(const int* __restrict__ ideg, float* __restrict__ dinv, int n) {
    int i = blockIdx.x * 256 + threadIdx.x;
    if (i < n) dinv[i] = rsqrtf((float)(ideg[i] + 1)); // +1 self loop
}

// out[d] = relu((h[d]*dinv[d] + sum h[s]*dinv[s]) * dinv[d] + bias)
__global__ __launch_bounds__(256) void k_gather(
    const float* __restrict__ h, const int* __restrict__ rowst,
    const int* __restrict__ elist, const float* __restrict__ dinv,
    const float* __restrict__ bias, float* __restrict__ out, int n)
{
    size_t gid = (size_t)blockIdx.x * 256 + threadIdx.x;
    int d = (int)(gid >> 5);
    if (d >= n) return;
    int l = (int)(gid & 31);
    const float4* hv = (const float4*)h;
    float dd = dinv[d];
    float4 self = hv[(size_t)d * 32 + l];
    float4 acc;
    acc.x = self.x * dd; acc.y = self.y * dd; acc.z = self.z * dd; acc.w = self.w * dd;
    int s0 = rowst[d], s1 = rowst[d + 1];
    for (int e = s0; e < s1; ++e) {
        int s = elist[e];
        float ds = dinv[s];
        float4 v = hv[(size_t)s * 32 + l];
        acc.x = fmaf(v.x, ds, acc.x);
        acc.y = fmaf(v.y, ds, acc.y);
        acc.z = fmaf(v.z, ds, acc.z);
        acc.w = fmaf(v.w, ds, acc.w);
    }
    const float4 b = ((const float4*)bias)[l];
    float4 y;
    y.x = fmaxf(fmaf(acc.x, dd, b.x), 0.f);
    y.y = fmaxf(fmaf(acc.y, dd, b.y), 0.f);
    y.z = fmaxf(fmaf(acc.z, dd, b.z), 0.f);
    y.w = fmaxf(fmaf(acc.w, dd, b.w), 0.f);
    ((float4*)out)[(size_t)d * 32 + l] = y;
}

// out[p] = relu(sum_{i in children(p)} Y[i])
__global__ __launch_bounds__(256) void k_poolgather(
    const float* __restrict__ Y, const int* __restrict__ rowst,
    const int* __restrict__ elist, float* __restrict__ out, int np)
{
    size_t gid = (size_t)blockIdx.x * 256 + threadIdx.x;
    int p = (int)(gid >> 5);
    if (p >= np) return;
    int l = (int)(gid & 31);
    const float4* yv = (const float4*)Y;
    float4 acc = {0.f, 0.f, 0.f, 0.f};
    int s0 = rowst[p], s1 = rowst[p + 1];
    for (int e = s0; e < s1; ++e) {
        int i = elist[e];
        float4 v = yv[(size_t)i * 32 + l];
        acc.x += v.x; acc.y += v.y; acc.z += v.z; acc.w += v.w;
    }
    float4 y;
    y.x = fmaxf(acc.x, 0.f); y.y = fmaxf(acc.y, 0.f);
    y.z = fmaxf(acc.z, 0.f); y.w = fmaxf(acc.w, 0.f);
    ((float4*)out)[(size_t)p * 32 + l] = y;
}

// sorted-key segmented sum: pl[bidx[r]][coloff+j] += src[r][j]
__global__ __launch_bounds__(128) void k_bpool_sorted(
    const float* __restrict__ src, const int* __restrict__ bidx,
    float* __restrict__ pl, int coloff, int n)
{
    int j = threadIdx.x;
    int r0 = blockIdx.x * 128;
    if (r0 >= n) return;
    int r1 = min(r0 + 128, n);
    float acc = 0.f;
    int prev = bidx[r0];
    for (int r = r0; r < r1; ++r) {
        int b = bidx[r];
        if (b != prev) {
            unsafeAtomicAdd(&pl[(size_t)prev * 384 + coloff + j], acc);
            acc = 0.f; prev = b;
        }
        acc += src[(size_t)r * 128 + j];
    }
    unsafeAtomicAdd(&pl[(size_t)prev * 384 + coloff + j], acc);
}

// small dense MLP: out[r][j] = (relu?)(A[r,:K] @ W[:,j] + b[j])
__global__ void k_mlp(const float* __restrict__ A, const float* __restrict__ W,
                      const float* __restrict__ b, float* __restrict__ out,
                      int K, int dorelu)
{
    __shared__ float as[384];
    int r = blockIdx.x, j = threadIdx.x;
    for (int i = j; i < K; i += 128) as[i] = A[(size_t)r * K + i];
    __syncthreads();
    float acc = b[j];
    for (int k = 0; k < K; k++) acc = fmaf(as[k], W[(size_t)k * 128 + j], acc);
    if (dorelu) acc = fmaxf(acc, 0.f);
    out[(size_t)r * 128 + j] = acc;
}

// ---------------- host-side helpers ------------------------------------------
static void build_csr(const int* key, const int* val, int E, int n,
                      int* ideg, int* rowst, int* curs, int* elist, int* bsum,
                      hipStream_t stream)
{
    hipMemsetAsync(ideg, 0, (size_t)n * 4, stream);
    k_count_int<<<(E + 255) / 256, 256, 0, stream>>>(key, ideg, E);
    int nb = (n + 1023) / 1024;
    k_scan_block<<<nb, 256, 0, stream>>>(ideg, rowst, bsum, n);
    k_scan_top<<<1, 256, 0, stream>>>(bsum, nb);
    k_scan_add<<<nb, 256, 0, stream>>>(rowst, curs, bsum, n, E);
    if (val) k_scatter<<<(E + 255) / 256, 256, 0, stream>>>(val, key, curs, elist, E);
    else     k_scatter_iota<<<(E + 255) / 256, 256, 0, stream>>>(key, curs, elist, E);
}

extern "C" void kernel_launch(void* const* d_in, const int* in_sizes, int n_in,
                              void* d_out, int out_size, void* d_ws, size_t ws_size,
                              hipStream_t stream)
{
    const float* x_raw  = (const float*)d_in[0];
    const float* W_des  = (const float*)d_in[1];
    const float* b_des  = (const float*)d_in[2];
    const float* W_twe  = (const float*)d_in[3];
    const float* b_twe  = (const float*)d_in[4];
    const float* W_num  = (const float*)d_in[5];
    const float* b_num  = (const float*)d_in[6];
    const float* W_cat  = (const float*)d_in[7];
    const float* b_cat  = (const float*)d_in[8];
    const float* W_in   = (const float*)d_in[9];
    const float* b_in   = (const float*)d_in[10];
    const float* prelua = (const float*)d_in[11];
    const float* W_conv = (const float*)d_in[12];
    const float* b_conv = (const float*)d_in[13];
    const float* Wc1    = (const float*)d_in[14];
    const float* bc1    = (const float*)d_in[15];
    const float* Wc2    = (const float*)d_in[16];
    const float* bc2    = (const float*)d_in[17];
    const int* nodelist = (const int*)d_in[18];
    const int* e0       = (const int*)d_in[19];
    const int* e1       = (const int*)d_in[20];
    const int* e2       = (const int*)d_in[21];
    const int* parent1  = (const int*)d_in[22];
    const int* parent2  = (const int*)d_in[23];
    const int* batch1   = (const int*)d_in[24];
    const int* batch2   = (const int*)d_in[25];

    // ---- workspace layout (~263 MB) ----
    float* ENC = (float*)d_ws;                 // 50000*128 (dead after L0 gemm)
    int* ELIST = (int*)d_ws;                   // CSR scratch aliases ENC region
    int* ROWST = ELIST + 1600000;
    int* CURS  = ROWST + 200001;
    int* IDEG  = CURS  + 200000;
    int* BSUM  = IDEG  + 200000;
    float* H    = ENC + (size_t)N_USERS * 128; // 200000*128
    float* Y    = H   + (size_t)NN0 * 128;     // 200000*128
    float* DINV = Y   + (size_t)NN0 * 128;     // 200000
    float* X1   = DINV + NN0;                  // 50000*128
    float* X2   = X1  + (size_t)NN1 * 128;     // 12500*128
    float* PL   = X2  + (size_t)NN2 * 128;     // 128*384
    float* Z    = PL  + 128 * 384;             // 128*128

    hipMemsetAsync(PL, 0, (size_t)128 * 384 * 4, stream);

    // ---- encoder (ENC live) ----
    k_enc<<<(N_USERS + 63) / 64, 256, 0, stream>>>(
        x_raw, W_des, b_des, W_twe, b_twe, W_num, b_num, W_cat, b_cat, ENC);
    k_gemm128<1><<<(N_USERS + 31) / 32, 256, 0, stream>>>(
        ENC, nullptr, W_in, b_in, prelua, ENC, N_USERS);

    // ---- layer 0 ----
    k_gemm128<0><<<(NN0 + 31) / 32, 256, 0, stream>>>(
        ENC, nodelist, W_conv, nullptr, nullptr, H, NN0);           // ENC dead after this
    build_csr(e0 + EE0, e0, EE0, NN0, IDEG, ROWST, CURS, ELIST, BSUM, stream);
    k_dinv<<<(NN0 + 255) / 256, 256, 0, stream>>>(IDEG, DINV, NN0);
    k_gather<<<(int)(((size_t)NN0 * 32 + 255) / 256), 256, 0, stream>>>(
        H, ROWST, ELIST, DINV, b_conv, Y, NN0);
    build_csr(parent1, nullptr, NN0, NN1, IDEG, ROWST, CURS, ELIST, BSUM, stream);
    k_poolgather<<<(int)(((size_t)NN1 * 32 + 255) / 256), 256, 0, stream>>>(
        Y, ROWST, ELIST, X1, NN1);

    // ---- layer 1 ----
    k_gemm128<0><<<(NN1 + 31) / 32, 256, 0, stream>>>(
        X1, nullptr, W_conv + 16384, nullptr, nullptr, H, NN1);
    build_csr(e1 + EE1, e1, EE1, NN1, IDEG, ROWST, CURS, ELIST, BSUM, stream);
    k_dinv<<<(NN1 + 255) / 256, 256, 0, stream>>>(IDEG, DINV, NN1);
    k_gather<<<(int)(((size_t)NN1 * 32 + 255) / 256), 256, 0, stream>>>(
        H, ROWST, ELIST, DINV, b_conv + 128, Y, NN1);
    build_csr(parent2, nullptr, NN1, NN2, IDEG, ROWST, CURS, ELIST, BSUM, stream);
    k_poolgather<<<(int)(((size_t)NN2 * 32 + 255) / 256), 256, 0, stream>>>(
        Y, ROWST, ELIST, X2, NN2);

    // ---- layer 2 ----
    k_gemm128<0><<<(NN2 + 31) / 32, 256, 0, stream>>>(
        X2, nullptr, W_conv + 32768, nullptr, nullptr, H, NN2);
    build_csr(e2 + EE2, e2, EE2, NN2, IDEG, ROWST, CURS, ELIST, BSUM, stream);
    k_dinv<<<(NN2 + 255) / 256, 256, 0, stream>>>(IDEG, DINV, NN2);
    k_gather<<<(int)(((size_t)NN2 * 32 + 255) / 256), 256, 0, stream>>>(
        H, ROWST, ELIST, DINV, b_conv + 256, Y, NN2);

    // ---- batch pooling (sorted keys -> segmented, few atomics) ----
    k_bpool_sorted<<<(NN1 + 127) / 128, 128, 0, stream>>>(X1, batch1, PL, 0, NN1);
    k_bpool_sorted<<<(NN2 + 127) / 128, 128, 0, stream>>>(X2, batch2, PL, 128, NN2);
    k_bpool_sorted<<<(NN2 + 127) / 128, 128, 0, stream>>>(Y,  batch2, PL, 256, NN2);

    // ---- final MLP ----
    k_mlp<<<128, 128, 0, stream>>>(PL, Wc1, bc1, Z, 384, 1);
    k_mlp<<<128, 128, 0, stream>>>(Z, Wc2, bc2, (float*)d_out, 128, 0);
}

// Round 4
// 1072.002 us; speedup vs baseline: 4.3605x; 1.0685x over previous
//
#include <hip/hip_runtime.h>

#define N_USERS 50000
#define NN0 200000
#define NN1 50000
#define NN2 12500
#define EE0 1600000
#define EE1 400000
#define EE2 100000

// Padded segment geometry for fused CSR builds (padded to 1024 multiples):
// seg:      0:e0        1:e1      2:e2      3:parent1  4:parent2
// n:        200000      50000     12500     50000      12500
// P(n):     200704      50176     13312     50176      13312
// deg off:  0           200704    250880    264192     314368   (total 327680)
// scan blk: 196         49        13        49         13       (cum 196,245,258,307,320)
// bsum off: 0           196       245       258        307
// E:        1600000     400000    100000    200000     50000    (cum 1.6M,2.0M,2.1M,2.3M,2.35M)
// el off:   0           1600000   2000000   2100000    2300000

// ---------------- encoder: h128[r] = leaky([d|t|n|c]) -------------------------
// 32 rows/block, 256 thr = 4 waves x 8 rows; lane l owns heavy col l (des|tweet)
// and light col 64+l (num|cat). X broadcast from LDS, W lane-distinct from LDS.
__global__ __launch_bounds__(256) void k_enc2(
    const float* __restrict__ xr,
    const float* __restrict__ Wd, const float* __restrict__ bd,
    const float* __restrict__ Wt, const float* __restrict__ bt,
    const float* __restrict__ Wn, const float* __restrict__ bn,
    const float* __restrict__ Wc, const float* __restrict__ bc,
    float* __restrict__ h128)
{
    __shared__ float Xs[32][68];   // cols 0-31 des chunk, 32-63 tweet chunk
    __shared__ float Wi[32][68];   // [k][lane]: lane<32 Wd, else Wt
    __shared__ float xnc[32][8];   // x[0..5] (num), x[774..775] (cat)
    __shared__ float Wl[8][64];    // light weights packed per lane

    int t = threadIdx.x;
    int lane = t & 63;
    int wv = t >> 6;
    int row8 = wv * 8;
    int base = blockIdx.x * 32;

    int srow = t >> 3;             // 0..31 staging row
    int sub = t & 7;
    int grow = base + srow;
    bool vrow = grow < N_USERS;
    const float* xrow = xr + (size_t)grow * 1544;

    if (t < 32) {
        int row = base + t;
        if (row < N_USERS) {
            const float* xp = xr + (size_t)row * 1544;
            float4 a = *(const float4*)xp;
            float2 b2 = *(const float2*)(xp + 4);
            float2 c2 = *(const float2*)(xp + 774);
            xnc[t][0] = a.x; xnc[t][1] = a.y; xnc[t][2] = a.z; xnc[t][3] = a.w;
            xnc[t][4] = b2.x; xnc[t][5] = b2.y; xnc[t][6] = c2.x; xnc[t][7] = c2.y;
        } else {
            #pragma unroll
            for (int k = 0; k < 8; k++) xnc[t][k] = 0.f;
        }
    } else if (t >= 192) {
        int l = t - 192;
        #pragma unroll
        for (int k = 0; k < 8; k++) {
            float w = 0.f;
            if (l < 32) { if (k < 6) w = Wn[k * 32 + l]; }
            else        { if (k >= 6) w = Wc[(k - 6) * 32 + (l - 32)]; }
            Wl[k][l] = w;
        }
    }

    float acc[8];
    #pragma unroll
    for (int r = 0; r < 8; r++) acc[r] = 0.f;
    int sel = (lane < 32) ? 0 : 32;

    for (int kc = 0; kc < 768; kc += 32) {
        __syncthreads();
        if (vrow) {
            if (sub < 4) {          // des: cols sub*8..+7, 16B-aligned (off 776)
                const float* pd = xrow + 776 + kc + sub * 8;
                *(float4*)&Xs[srow][sub * 8]     = *(const float4*)pd;
                *(float4*)&Xs[srow][sub * 8 + 4] = *(const float4*)(pd + 4);
            } else {                // tweet: cols 32+q*8, 8B-aligned (off 6)
                int q = sub - 4;
                const float* pt = xrow + 6 + kc + q * 8;
                *(float2*)&Xs[srow][32 + q * 8]     = *(const float2*)pt;
                *(float2*)&Xs[srow][32 + q * 8 + 2] = *(const float2*)(pt + 2);
                *(float2*)&Xs[srow][32 + q * 8 + 4] = *(const float2*)(pt + 4);
                *(float2*)&Xs[srow][32 + q * 8 + 6] = *(const float2*)(pt + 6);
            }
        }
        #pragma unroll
        for (int h = 0; h < 2; h++) {
            int fi = t + h * 256;          // 512 float4s = 32k x 64c
            int k = fi >> 4;
            int c4 = (fi & 15) * 4;
            float4 w = (c4 < 32) ? *(const float4*)(Wd + (size_t)(kc + k) * 32 + c4)
                                 : *(const float4*)(Wt + (size_t)(kc + k) * 32 + (c4 - 32));
            *(float4*)&Wi[k][c4] = w;
        }
        __syncthreads();
        #pragma unroll
        for (int kk = 0; kk < 4; kk++) {
            float w0 = Wi[kk * 8 + 0][lane], w1 = Wi[kk * 8 + 1][lane],
                  w2 = Wi[kk * 8 + 2][lane], w3 = Wi[kk * 8 + 3][lane],
                  w4 = Wi[kk * 8 + 4][lane], w5 = Wi[kk * 8 + 5][lane],
                  w6 = Wi[kk * 8 + 6][lane], w7 = Wi[kk * 8 + 7][lane];
            #pragma unroll
            for (int r = 0; r < 8; r++) {
                const float* xp = &Xs[row8 + r][sel + kk * 8];
                float4 xA = *(const float4*)xp;
                float4 xB = *(const float4*)(xp + 4);
                float a = acc[r];
                a = fmaf(xA.x, w0, a); a = fmaf(xA.y, w1, a);
                a = fmaf(xA.z, w2, a); a = fmaf(xA.w, w3, a);
                a = fmaf(xB.x, w4, a); a = fmaf(xB.y, w5, a);
                a = fmaf(xB.z, w6, a); a = fmaf(xB.w, w7, a);
                acc[r] = a;
            }
        }
    }

    float bh = (lane < 32) ? bd[lane] : bt[lane - 32];
    float bl = (lane < 32) ? bn[lane] : bc[lane - 32];
    float wl[8];
    #pragma unroll
    for (int k = 0; k < 8; k++) wl[k] = Wl[k][lane];

    #pragma unroll
    for (int r = 0; r < 8; r++) {
        int row = base + row8 + r;
        if (row >= N_USERS) break;
        float hv = acc[r] + bh;
        hv = hv > 0.f ? hv : 0.01f * hv;
        float lv = bl;
        #pragma unroll
        for (int k = 0; k < 8; k++) lv = fmaf(xnc[row8 + r][k], wl[k], lv);
        lv = lv > 0.f ? lv : 0.01f * lv;
        h128[(size_t)row * 128 + lane] = hv;
        h128[(size_t)row * 128 + 64 + lane] = lv;
    }
}

// ---------------- [n,128] @ [128,128] GEMM, optional row gather --------------
template<int EPI> // 0: plain, 1: prelu(x+b)
__global__ __launch_bounds__(256) void k_gemm128(
    const float* __restrict__ X, const int* __restrict__ idx,
    const float* __restrict__ W, const float* __restrict__ bias,
    const float* __restrict__ pa, float* __restrict__ OUT, int n)
{
    __shared__ float xs[32][128];
    int base = blockIdx.x * 32;
    for (int i = threadIdx.x; i < 32 * 128; i += 256) {
        int r = i >> 7, c = i & 127;
        int row = base + r;
        float v = 0.f;
        if (row < n) {
            int srow = idx ? idx[row] : row;
            v = X[(size_t)srow * 128 + c];
        }
        xs[r][c] = v;
    }
    __syncthreads();
    int j = threadIdx.x & 127;
    int rh = (threadIdx.x >> 7) * 16;
    float acc[16];
    #pragma unroll
    for (int r = 0; r < 16; r++) acc[r] = 0.f;
    for (int k = 0; k < 128; k += 4) {
        float w0 = W[(size_t)(k + 0) * 128 + j];
        float w1 = W[(size_t)(k + 1) * 128 + j];
        float w2 = W[(size_t)(k + 2) * 128 + j];
        float w3 = W[(size_t)(k + 3) * 128 + j];
        #pragma unroll
        for (int r = 0; r < 16; r++) {
            float4 x4 = *(const float4*)(&xs[rh + r][k]);
            acc[r] = fmaf(x4.w, w3, fmaf(x4.z, w2, fmaf(x4.y, w1, fmaf(x4.x, w0, acc[r]))));
        }
    }
    #pragma unroll
    for (int r = 0; r < 16; r++) {
        int row = base + rh + r;
        if (row < n) {
            float v = acc[r];
            if (EPI == 1) { v += bias[j]; v = v > 0.f ? v : pa[j] * v; }
            OUT[(size_t)row * 128 + j] = v;
        }
    }
}

// ---------------- fused CSR build over 5 segments ----------------------------
__device__ __forceinline__ void seg_of_scanblk(int b, int& doff, int& bsoff, int& lb) {
    if (b < 196)      { doff = 0;      bsoff = 0;   lb = b; }
    else if (b < 245) { doff = 200704; bsoff = 196; lb = b - 196; }
    else if (b < 258) { doff = 250880; bsoff = 245; lb = b - 245; }
    else if (b < 307) { doff = 264192; bsoff = 258; lb = b - 258; }
    else              { doff = 314368; bsoff = 307; lb = b - 307; }
}

__global__ void k_count_all(
    const int* __restrict__ d0, const int* __restrict__ d1, const int* __restrict__ d2,
    const int* __restrict__ p1, const int* __restrict__ p2, int* __restrict__ degs)
{
    int gid = blockIdx.x * 256 + threadIdx.x;
    if (gid < 1600000)      atomicAdd(&degs[d0[gid]], 1);
    else if (gid < 2000000) atomicAdd(&degs[200704 + d1[gid - 1600000]], 1);
    else if (gid < 2100000) atomicAdd(&degs[250880 + d2[gid - 2000000]], 1);
    else if (gid < 2300000) atomicAdd(&degs[264192 + p1[gid - 2100000]], 1);
    else if (gid < 2350000) atomicAdd(&degs[314368 + p2[gid - 2300000]], 1);
}

__global__ __launch_bounds__(256) void k_scan_all(
    const int* __restrict__ degs, int* __restrict__ rowsts, int* __restrict__ bsums)
{
    __shared__ int sh[256];
    int doff, bsoff, lb;
    seg_of_scanblk(blockIdx.x, doff, bsoff, lb);
    int t = threadIdx.x;
    int base = doff + lb * 1024 + t * 4;
    int v[4], s = 0;
    #pragma unroll
    for (int k = 0; k < 4; k++) { v[k] = degs[base + k]; s += v[k]; }
    sh[t] = s;
    __syncthreads();
    for (int off = 1; off < 256; off <<= 1) {
        int x = 0;
        if (t >= off) x = sh[t - off];
        __syncthreads();
        if (t >= off) sh[t] += x;
        __syncthreads();
    }
    int ex = sh[t] - s;
    if (t == 255) bsums[bsoff + lb] = sh[255];
    #pragma unroll
    for (int k = 0; k < 4; k++) { rowsts[base + k] = ex; ex += v[k]; }
}

__global__ __launch_bounds__(256) void k_scantop_all(int* __restrict__ bsums)
{
    __shared__ int sh[256];
    int b = blockIdx.x;
    int off0, nb;
    if (b == 0)      { off0 = 0;   nb = 196; }
    else if (b == 1) { off0 = 196; nb = 49; }
    else if (b == 2) { off0 = 245; nb = 13; }
    else if (b == 3) { off0 = 258; nb = 49; }
    else             { off0 = 307; nb = 13; }
    int t = threadIdx.x;
    int v = (t < nb) ? bsums[off0 + t] : 0;
    sh[t] = v;
    __syncthreads();
    for (int off = 1; off < 256; off <<= 1) {
        int x = 0;
        if (t >= off) x = sh[t - off];
        __syncthreads();
        if (t >= off) sh[t] += x;
        __syncthreads();
    }
    if (t < nb) bsums[off0 + t] = sh[t] - v; // exclusive
}

// adds block offsets, fills curs, and computes dinv for segs 0-2
__global__ __launch_bounds__(256) void k_scanadd_all(
    int* __restrict__ rowsts, int* __restrict__ curss, const int* __restrict__ bsums,
    const int* __restrict__ degs, float* __restrict__ dinvs)
{
    int doff, bsoff, lb;
    seg_of_scanblk(blockIdx.x, doff, bsoff, lb);
    int t = threadIdx.x;
    int base = doff + lb * 1024 + t * 4;
    int add = bsums[bsoff + lb];
    bool dodinv = (doff <= 250880);
    #pragma unroll
    for (int k = 0; k < 4; k++) {
        int i = base + k;
        int r = rowsts[i] + add;
        rowsts[i] = r;
        curss[i] = r;
        if (dodinv) dinvs[i] = rsqrtf((float)degs[i] + 1.0f);
    }
}

__global__ void k_scatter_all(
    const int* __restrict__ s0, const int* __restrict__ d0,
    const int* __restrict__ s1, const int* __restrict__ d1,
    const int* __restrict__ s2, const int* __restrict__ d2,
    const int* __restrict__ p1, const int* __restrict__ p2,
    int* __restrict__ curss, int* __restrict__ elists)
{
    int gid = blockIdx.x * 256 + threadIdx.x;
    if (gid < 1600000) {
        int p = atomicAdd(&curss[d0[gid]], 1);
        elists[p] = s0[gid];
    } else if (gid < 2000000) {
        int i = gid - 1600000;
        int p = atomicAdd(&curss[200704 + d1[i]], 1);
        elists[1600000 + p] = s1[i];
    } else if (gid < 2100000) {
        int i = gid - 2000000;
        int p = atomicAdd(&curss[250880 + d2[i]], 1);
        elists[2000000 + p] = s2[i];
    } else if (gid < 2300000) {
        int i = gid - 2100000;
        int p = atomicAdd(&curss[264192 + p1[i]], 1);
        elists[2100000 + p] = i;
    } else if (gid < 2350000) {
        int i = gid - 2300000;
        int p = atomicAdd(&curss[314368 + p2[i]], 1);
        elists[2300000 + p] = i;
    }
}

// ---------------- GCN pieces -------------------------------------------------
// out[d] = relu((h[d]*dinv[d] + sum h[s]*dinv[s]) * dinv[d] + bias)
__global__ __launch_bounds__(256) void k_gather(
    const float* __restrict__ h, const int* __restrict__ rowst,
    const int* __restrict__ elist, const float* __restrict__ dinv,
    const float* __restrict__ bias, float* __restrict__ out, int n)
{
    size_t gid = (size_t)blockIdx.x * 256 + threadIdx.x;
    int d = (int)(gid >> 5);
    if (d >= n) return;
    int l = (int)(gid & 31);
    const float4* hv = (const float4*)h;
    float dd = dinv[d];
    float4 self = hv[(size_t)d * 32 + l];
    float4 acc;
    acc.x = self.x * dd; acc.y = self.y * dd; acc.z = self.z * dd; acc.w = self.w * dd;
    int s0 = rowst[d], s1 = rowst[d + 1];
    for (int e = s0; e < s1; ++e) {
        int s = elist[e];
        float ds = dinv[s];
        float4 v = hv[(size_t)s * 32 + l];
        acc.x = fmaf(v.x, ds, acc.x);
        acc.y = fmaf(v.y, ds, acc.y);
        acc.z = fmaf(v.z, ds, acc.z);
        acc.w = fmaf(v.w, ds, acc.w);
    }
    const float4 b = ((const float4*)bias)[l];
    float4 y;
    y.x = fmaxf(fmaf(acc.x, dd, b.x), 0.f);
    y.y = fmaxf(fmaf(acc.y, dd, b.y), 0.f);
    y.z = fmaxf(fmaf(acc.z, dd, b.z), 0.f);
    y.w = fmaxf(fmaf(acc.w, dd, b.w), 0.f);
    ((float4*)out)[(size_t)d * 32 + l] = y;
}

// out[p] = relu(sum_{i in children(p)} Y[i])
__global__ __launch_bounds__(256) void k_poolgather(
    const float* __restrict__ Y, const int* __restrict__ rowst,
    const int* __restrict__ elist, float* __restrict__ out, int np)
{
    size_t gid = (size_t)blockIdx.x * 256 + threadIdx.x;
    int p = (int)(gid >> 5);
    if (p >= np) return;
    int l = (int)(gid & 31);
    const float4* yv = (const float4*)Y;
    float4 acc = {0.f, 0.f, 0.f, 0.f};
    int s0 = rowst[p], s1 = rowst[p + 1];
    for (int e = s0; e < s1; ++e) {
        int i = elist[e];
        float4 v = yv[(size_t)i * 32 + l];
        acc.x += v.x; acc.y += v.y; acc.z += v.z; acc.w += v.w;
    }
    float4 y;
    y.x = fmaxf(acc.x, 0.f); y.y = fmaxf(acc.y, 0.f);
    y.z = fmaxf(acc.z, 0.f); y.w = fmaxf(acc.w, 0.f);
    ((float4*)out)[(size_t)p * 32 + l] = y;
}

// fused sorted-key batch pooling for all 3 sources
__global__ __launch_bounds__(128) void k_bpool_all(
    const float* __restrict__ X1, const float* __restrict__ X2, const float* __restrict__ Y2,
    const int* __restrict__ b1, const int* __restrict__ b2, float* __restrict__ pl)
{
    int b = blockIdx.x;
    const float* src; const int* bidx; int coloff, n, r0;
    if (b < 391)      { src = X1; bidx = b1; coloff = 0;   n = 50000; r0 = b * 128; }
    else if (b < 489) { src = X2; bidx = b2; coloff = 128; n = 12500; r0 = (b - 391) * 128; }
    else              { src = Y2; bidx = b2; coloff = 256; n = 12500; r0 = (b - 489) * 128; }
    if (r0 >= n) return;
    int j = threadIdx.x;
    int r1 = min(r0 + 128, n);
    float acc = 0.f;
    int prev = bidx[r0];
    for (int r = r0; r < r1; ++r) {
        int bb = bidx[r];
        if (bb != prev) {
            unsafeAtomicAdd(&pl[(size_t)prev * 384 + coloff + j], acc);
            acc = 0.f; prev = bb;
        }
        acc += src[(size_t)r * 128 + j];
    }
    unsafeAtomicAdd(&pl[(size_t)prev * 384 + coloff + j], acc);
}

// small dense MLP: out[r][j] = (relu?)(A[r,:K] @ W[:,j] + b[j])
__global__ void k_mlp(const float* __restrict__ A, const float* __restrict__ W,
                      const float* __restrict__ b, float* __restrict__ out,
                      int K, int dorelu)
{
    __shared__ float as[384];
    int r = blockIdx.x, j = threadIdx.x;
    for (int i = j; i < K; i += 128) as[i] = A[(size_t)r * K + i];
    __syncthreads();
    float acc = b[j];
    for (int k = 0; k < K; k++) acc = fmaf(as[k], W[(size_t)k * 128 + j], acc);
    if (dorelu) acc = fmaxf(acc, 0.f);
    out[(size_t)r * 128 + j] = acc;
}

extern "C" void kernel_launch(void* const* d_in, const int* in_sizes, int n_in,
                              void* d_out, int out_size, void* d_ws, size_t ws_size,
                              hipStream_t stream)
{
    const float* x_raw  = (const float*)d_in[0];
    const float* W_des  = (const float*)d_in[1];
    const float* b_des  = (const float*)d_in[2];
    const float* W_twe  = (const float*)d_in[3];
    const float* b_twe  = (const float*)d_in[4];
    const float* W_num  = (const float*)d_in[5];
    const float* b_num  = (const float*)d_in[6];
    const float* W_cat  = (const float*)d_in[7];
    const float* b_cat  = (const float*)d_in[8];
    const float* W_in   = (const float*)d_in[9];
    const float* b_in   = (const float*)d_in[10];
    const float* prelua = (const float*)d_in[11];
    const float* W_conv = (const float*)d_in[12];
    const float* b_conv = (const float*)d_in[13];
    const float* Wc1    = (const float*)d_in[14];
    const float* bc1    = (const float*)d_in[15];
    const float* Wc2    = (const float*)d_in[16];
    const float* bc2    = (const float*)d_in[17];
    const int* nodelist = (const int*)d_in[18];
    const int* e0       = (const int*)d_in[19];
    const int* e1       = (const int*)d_in[20];
    const int* e2       = (const int*)d_in[21];
    const int* parent1  = (const int*)d_in[22];
    const int* parent2  = (const int*)d_in[23];
    const int* batch1   = (const int*)d_in[24];
    const int* batch2   = (const int*)d_in[25];

    // ---- workspace layout (~263 MB) ----
    float* WS = (float*)d_ws;
    float* ENC = WS;                           // 6,400,000 floats; dead after gemm L0
    // CSR scratch aliases ENC region (used only after ENC dead):
    int*   DEGS   = (int*)d_ws;                // 327680
    int*   ROWSTS = DEGS + 327680;             // 327680
    int*   CURSS  = ROWSTS + 327680;           // 327680
    float* DINVS  = (float*)(CURSS + 327680);  // 264192
    int*   BSUMS  = (int*)(DINVS + 264192);    // 512
    int*   ELISTS = BSUMS + 512;               // 2,350,000  (total 14.4 MB < 25.6 MB)
    float* H  = WS + 6400000;                  // 200000*128
    float* Y  = H + 25600000;                  // 200000*128
    float* X1 = Y + 25600000;                  // 50000*128
    float* X2 = X1 + 6400000;                  // 12500*128
    float* PL = X2 + 1600000;                  // 128*384
    float* Z  = PL + 49152;                    // 128*128

    hipMemsetAsync(PL, 0, (size_t)128 * 384 * 4, stream);

    // ---- encoder (ENC live) ----
    k_enc2<<<(N_USERS + 31) / 32, 256, 0, stream>>>(
        x_raw, W_des, b_des, W_twe, b_twe, W_num, b_num, W_cat, b_cat, ENC);
    k_gemm128<1><<<(N_USERS + 31) / 32, 256, 0, stream>>>(
        ENC, nullptr, W_in, b_in, prelua, ENC, N_USERS);

    // ---- layer 0 GEMM (last use of ENC) ----
    k_gemm128<0><<<(NN0 + 31) / 32, 256, 0, stream>>>(
        ENC, nodelist, W_conv, nullptr, nullptr, H, NN0);

    // ---- fused CSR builds for e0,e1,e2,parent1,parent2 (+dinv) ----
    hipMemsetAsync(DEGS, 0, (size_t)327680 * 4, stream);
    k_count_all<<<(2350000 + 255) / 256, 256, 0, stream>>>(
        e0 + EE0, e1 + EE1, e2 + EE2, parent1, parent2, DEGS);
    k_scan_all<<<320, 256, 0, stream>>>(DEGS, ROWSTS, BSUMS);
    k_scantop_all<<<5, 256, 0, stream>>>(BSUMS);
    k_scanadd_all<<<320, 256, 0, stream>>>(ROWSTS, CURSS, BSUMS, DEGS, DINVS);
    k_scatter_all<<<(2350000 + 255) / 256, 256, 0, stream>>>(
        e0, e0 + EE0, e1, e1 + EE1, e2, e2 + EE2, parent1, parent2, CURSS, ELISTS);

    // ---- layer 0 aggregate + pool ----
    k_gather<<<(int)(((size_t)NN0 * 32 + 255) / 256), 256, 0, stream>>>(
        H, ROWSTS, ELISTS, DINVS, b_conv, Y, NN0);
    k_poolgather<<<(int)(((size_t)NN1 * 32 + 255) / 256), 256, 0, stream>>>(
        Y, ROWSTS + 264192, ELISTS + 2100000, X1, NN1);

    // ---- layer 1 ----
    k_gemm128<0><<<(NN1 + 31) / 32, 256, 0, stream>>>(
        X1, nullptr, W_conv + 16384, nullptr, nullptr, H, NN1);
    k_gather<<<(int)(((size_t)NN1 * 32 + 255) / 256), 256, 0, stream>>>(
        H, ROWSTS + 200704, ELISTS + 1600000, DINVS + 200704, b_conv + 128, Y, NN1);
    k_poolgather<<<(int)(((size_t)NN2 * 32 + 255) / 256), 256, 0, stream>>>(
        Y, ROWSTS + 314368, ELISTS + 2300000, X2, NN2);

    // ---- layer 2 ----
    k_gemm128<0><<<(NN2 + 31) / 32, 256, 0, stream>>>(
        X2, nullptr, W_conv + 32768, nullptr, nullptr, H, NN2);
    k_gather<<<(int)(((size_t)NN2 * 32 + 255) / 256), 256, 0, stream>>>(
        H, ROWSTS + 250880, ELISTS + 2000000, DINVS + 250880, b_conv + 256, Y, NN2);

    // ---- batch pooling (fused, sorted keys) ----
    k_bpool_all<<<587, 128, 0, stream>>>(X1, X2, Y, batch1, batch2, PL);

    // ---- final MLP ----
    k_mlp<<<128, 128, 0, stream>>>(PL, Wc1, bc1, Z, 384, 1);
    k_mlp<<<128, 128, 0, stream>>>(Z, Wc2, bc2, (float*)d_out, 128, 0);
}

// Round 6
// 850.514 us; speedup vs baseline: 5.4960x; 1.2604x over previous
//
#include <hip/hip_runtime.h>

#define N_USERS 50000
#define NN0 200000
#define NN1 50000
#define NN2 12500
#define EE0 1600000
#define EE1 400000
#define EE2 100000

// Padded segment geometry for fused CSR builds (padded to 1024 multiples):
// seg:      0:e0        1:e1      2:e2      3:parent1  4:parent2
// deg off:  0           200704    250880    264192     314368   (total 327680)
// scan blk: 196         49        13        49         13       (cum 196,245,258,307,320)
// bsum off: 0           196       245       258        307
// el off:   0           1600000   2000000   2100000    2300000

// ---------------- encoder: h128[r] = leaky([d|t|n|c]) -------------------------
// 64 rows x 64 heavy cols per block; thread = 4 rows x 4 cols (16 FMA per
// X-b128 + W-b128 pair -> VALU-bound). Light cols (num/cat, K=8) in epilogue.
__global__ __launch_bounds__(256) void k_enc3(
    const float* __restrict__ xr,
    const float* __restrict__ Wd, const float* __restrict__ bd,
    const float* __restrict__ Wt, const float* __restrict__ bt,
    const float* __restrict__ Wn, const float* __restrict__ bn,
    const float* __restrict__ Wc, const float* __restrict__ bc,
    float* __restrict__ h128)
{
    __shared__ float XsD[32][68];  // [k][row] des chunk (transposed)
    __shared__ float XsT[32][68];  // [k][row] tweet chunk
    __shared__ float Ws[32][68];   // [k][col 0..63] = [Wd|Wt]
    __shared__ float xnc[64][8];   // num(6)+cat(2) inputs
    __shared__ float Wl[8][64];    // light weights, zero-padded per plane

    int t = threadIdx.x;
    int cg = t & 15, rg = t >> 4;  // cols 4cg..+3, rows 4rg..+3
    int base = blockIdx.x * 64;

    if (t < 64) {
        int row = base + t;
        if (row < N_USERS) {
            const float* xp = xr + (size_t)row * 1544;
            float4 a = *(const float4*)xp;
            float2 b2 = *(const float2*)(xp + 4);
            float2 c2 = *(const float2*)(xp + 774);
            xnc[t][0] = a.x; xnc[t][1] = a.y; xnc[t][2] = a.z; xnc[t][3] = a.w;
            xnc[t][4] = b2.x; xnc[t][5] = b2.y; xnc[t][6] = c2.x; xnc[t][7] = c2.y;
        } else {
            #pragma unroll
            for (int k = 0; k < 8; k++) xnc[t][k] = 0.f;
        }
    } else if (t >= 192) {
        int l = t - 192;
        #pragma unroll
        for (int k = 0; k < 8; k++) {
            float w = 0.f;
            if (l < 32) { if (k < 6) w = Wn[k * 32 + l]; }
            else        { if (k >= 6) w = Wc[(k - 6) * 32 + (l - 32)]; }
            Wl[k][l] = w;
        }
    }

    float acc[4][4];
    #pragma unroll
    for (int r = 0; r < 4; r++)
        #pragma unroll
        for (int c = 0; c < 4; c++) acc[r][c] = 0.f;

    for (int kc = 0; kc < 768; kc += 32) {
        __syncthreads();
        // stage X transposed: 2 slots/thread, each = one (row, 4k) group
        #pragma unroll
        for (int h = 0; h < 2; h++) {
            int fi = t * 2 + h;
            int row = fi >> 3, q = fi & 7;
            int grow = base + row;
            float4 vd = {0.f, 0.f, 0.f, 0.f};
            float2 va = {0.f, 0.f}, vb = {0.f, 0.f};
            if (grow < N_USERS) {
                const float* xp = xr + (size_t)grow * 1544 + kc + q * 4;
                vd = *(const float4*)(xp + 776);  // 16B aligned
                va = *(const float2*)(xp + 6);    // 8B aligned
                vb = *(const float2*)(xp + 8);
            }
            int k0 = q * 4;
            XsD[k0 + 0][row] = vd.x; XsD[k0 + 1][row] = vd.y;
            XsD[k0 + 2][row] = vd.z; XsD[k0 + 3][row] = vd.w;
            XsT[k0 + 0][row] = va.x; XsT[k0 + 1][row] = va.y;
            XsT[k0 + 2][row] = vb.x; XsT[k0 + 3][row] = vb.y;
        }
        // stage W chunk [32k][64c]  (512 float4 = 2 x 256 threads)
        #pragma unroll
        for (int h = 0; h < 2; h++) {
            int fi = t + h * 256;
            int k = fi >> 4, c4 = (fi & 15) * 4;
            float4 w = (c4 < 32) ? *(const float4*)(Wd + (size_t)(kc + k) * 32 + c4)
                                 : *(const float4*)(Wt + (size_t)(kc + k) * 32 + (c4 - 32));
            *(float4*)&Ws[k][c4] = w;
        }
        __syncthreads();

        const float* Xp = (cg < 8) ? &XsD[0][0] : &XsT[0][0];
        #pragma unroll 8
        for (int k = 0; k < 32; k++) {
            float4 xv = *(const float4*)(Xp + k * 68 + rg * 4);
            float4 wv = *(const float4*)&Ws[k][cg * 4];
            acc[0][0] = fmaf(xv.x, wv.x, acc[0][0]);
            acc[0][1] = fmaf(xv.x, wv.y, acc[0][1]);
            acc[0][2] = fmaf(xv.x, wv.z, acc[0][2]);
            acc[0][3] = fmaf(xv.x, wv.w, acc[0][3]);
            acc[1][0] = fmaf(xv.y, wv.x, acc[1][0]);
            acc[1][1] = fmaf(xv.y, wv.y, acc[1][1]);
            acc[1][2] = fmaf(xv.y, wv.z, acc[1][2]);
            acc[1][3] = fmaf(xv.y, wv.w, acc[1][3]);
            acc[2][0] = fmaf(xv.z, wv.x, acc[2][0]);
            acc[2][1] = fmaf(xv.z, wv.y, acc[2][1]);
            acc[2][2] = fmaf(xv.z, wv.z, acc[2][2]);
            acc[2][3] = fmaf(xv.z, wv.w, acc[2][3]);
            acc[3][0] = fmaf(xv.w, wv.x, acc[3][0]);
            acc[3][1] = fmaf(xv.w, wv.y, acc[3][1]);
            acc[3][2] = fmaf(xv.w, wv.z, acc[3][2]);
            acc[3][3] = fmaf(xv.w, wv.w, acc[3][3]);
        }
    }

    // epilogue
    float bh[4], bl[4], wlv[8][4];
    #pragma unroll
    for (int c = 0; c < 4; c++) {
        int j = cg * 4 + c;
        bh[c] = (j < 32) ? bd[j] : bt[j - 32];
        bl[c] = (j < 32) ? bn[j] : bc[j - 32];
        #pragma unroll
        for (int k = 0; k < 8; k++) wlv[k][c] = Wl[k][j];
    }
    #pragma unroll
    for (int r = 0; r < 4; r++) {
        int lr = rg * 4 + r;
        int row = base + lr;
        if (row >= N_USERS) break;
        float4 hv;
        float* ph = &hv.x;
        #pragma unroll
        for (int c = 0; c < 4; c++) {
            float v = acc[r][c] + bh[c];
            ph[c] = v > 0.f ? v : 0.01f * v;
        }
        *(float4*)(h128 + (size_t)row * 128 + cg * 4) = hv;
        float4 lv;
        float* pl = &lv.x;
        #pragma unroll
        for (int c = 0; c < 4; c++) {
            float v = bl[c];
            #pragma unroll
            for (int k = 0; k < 8; k++) v = fmaf(xnc[lr][k], wlv[k][c], v);
            pl[c] = v > 0.f ? v : 0.01f * v;
        }
        *(float4*)(h128 + (size_t)row * 128 + 64 + cg * 4) = lv;
    }
}

// ---------------- [n,128] @ [128,128] GEMM, 4x4 register tile ----------------
template<int EPI> // 0: plain, 1: prelu(x+b)
__global__ __launch_bounds__(256) void k_gemmT(
    const float* X, const float* __restrict__ W, const float* __restrict__ bias,
    const float* __restrict__ pa, float* OUT, int n)
{
    __shared__ float Xs[32][132];  // [row][k] whole K=128
    __shared__ float Ws[32][132];  // [k][col] chunk
    int t = threadIdx.x;
    int cg = t & 31, rg = t >> 5;  // cols 4cg..+3, rows 4rg..+3
    int base = blockIdx.x * 32;

    #pragma unroll
    for (int h = 0; h < 4; h++) {
        int fi = t + h * 256;
        int row = fi >> 5, q = fi & 31;
        float4 v = {0.f, 0.f, 0.f, 0.f};
        if (base + row < n) v = *(const float4*)(X + (size_t)(base + row) * 128 + q * 4);
        *(float4*)&Xs[row][q * 4] = v;
    }

    float acc[4][4];
    #pragma unroll
    for (int r = 0; r < 4; r++)
        #pragma unroll
        for (int c = 0; c < 4; c++) acc[r][c] = 0.f;

    for (int kc = 0; kc < 128; kc += 32) {
        __syncthreads();
        // stage W chunk: 32 k-rows x 128 cols = 1024 float4 = 4 x 256 threads
        #pragma unroll
        for (int h = 0; h < 4; h++) {
            int fi = t + h * 256;
            int k = fi >> 5, q = fi & 31;
            *(float4*)&Ws[k][q * 4] = *(const float4*)(W + (size_t)(kc + k) * 128 + q * 4);
        }
        __syncthreads();
        #pragma unroll
        for (int k4 = 0; k4 < 8; k4++) {
            int k = k4 * 4;
            float4 w0 = *(const float4*)&Ws[k + 0][cg * 4];
            float4 w1 = *(const float4*)&Ws[k + 1][cg * 4];
            float4 w2 = *(const float4*)&Ws[k + 2][cg * 4];
            float4 w3 = *(const float4*)&Ws[k + 3][cg * 4];
            #pragma unroll
            for (int r = 0; r < 4; r++) {
                float4 xv = *(const float4*)&Xs[rg * 4 + r][kc + k];
                acc[r][0] = fmaf(xv.w, w3.x, fmaf(xv.z, w2.x, fmaf(xv.y, w1.x, fmaf(xv.x, w0.x, acc[r][0]))));
                acc[r][1] = fmaf(xv.w, w3.y, fmaf(xv.z, w2.y, fmaf(xv.y, w1.y, fmaf(xv.x, w0.y, acc[r][1]))));
                acc[r][2] = fmaf(xv.w, w3.z, fmaf(xv.z, w2.z, fmaf(xv.y, w1.z, fmaf(xv.x, w0.z, acc[r][2]))));
                acc[r][3] = fmaf(xv.w, w3.w, fmaf(xv.z, w2.w, fmaf(xv.y, w1.w, fmaf(xv.x, w0.w, acc[r][3]))));
            }
        }
    }

    float4 bv = {0.f, 0.f, 0.f, 0.f}, pv = {0.f, 0.f, 0.f, 0.f};
    if (EPI == 1) { bv = *(const float4*)(bias + cg * 4); pv = *(const float4*)(pa + cg * 4); }
    #pragma unroll
    for (int r = 0; r < 4; r++) {
        int row = base + rg * 4 + r;
        if (row >= n) break;
        float4 v;
        if (EPI == 1) {
            v.x = acc[r][0] + bv.x; v.x = v.x > 0.f ? v.x : pv.x * v.x;
            v.y = acc[r][1] + bv.y; v.y = v.y > 0.f ? v.y : pv.y * v.y;
            v.z = acc[r][2] + bv.z; v.z = v.z > 0.f ? v.z : pv.z * v.z;
            v.w = acc[r][3] + bv.w; v.w = v.w > 0.f ? v.w : pv.w * v.w;
        } else {
            v.x = acc[r][0]; v.y = acc[r][1]; v.z = acc[r][2]; v.w = acc[r][3];
        }
        *(float4*)(OUT + (size_t)row * 128 + cg * 4) = v;
    }
}

// ---------------- fused CSR build over 5 segments ----------------------------
__device__ __forceinline__ void seg_of_scanblk(int b, int& doff, int& bsoff, int& lb) {
    if (b < 196)      { doff = 0;      bsoff = 0;   lb = b; }
    else if (b < 245) { doff = 200704; bsoff = 196; lb = b - 196; }
    else if (b < 258) { doff = 250880; bsoff = 245; lb = b - 245; }
    else if (b < 307) { doff = 264192; bsoff = 258; lb = b - 258; }
    else              { doff = 314368; bsoff = 307; lb = b - 307; }
}

__global__ void k_count_all(
    const int* __restrict__ d0, const int* __restrict__ d1, const int* __restrict__ d2,
    const int* __restrict__ p1, const int* __restrict__ p2, int* __restrict__ degs)
{
    int gid = blockIdx.x * 256 + threadIdx.x;
    if (gid < 1600000)      atomicAdd(&degs[d0[gid]], 1);
    else if (gid < 2000000) atomicAdd(&degs[200704 + d1[gid - 1600000]], 1);
    else if (gid < 2100000) atomicAdd(&degs[250880 + d2[gid - 2000000]], 1);
    else if (gid < 2300000) atomicAdd(&degs[264192 + p1[gid - 2100000]], 1);
    else if (gid < 2350000) atomicAdd(&degs[314368 + p2[gid - 2300000]], 1);
}

__global__ __launch_bounds__(256) void k_scan_all(
    const int* __restrict__ degs, int* __restrict__ rowsts, int* __restrict__ bsums)
{
    __shared__ int sh[256];
    int doff, bsoff, lb;
    seg_of_scanblk(blockIdx.x, doff, bsoff, lb);
    int t = threadIdx.x;
    int base = doff + lb * 1024 + t * 4;
    int v[4], s = 0;
    #pragma unroll
    for (int k = 0; k < 4; k++) { v[k] = degs[base + k]; s += v[k]; }
    sh[t] = s;
    __syncthreads();
    for (int off = 1; off < 256; off <<= 1) {
        int x = 0;
        if (t >= off) x = sh[t - off];
        __syncthreads();
        if (t >= off) sh[t] += x;
        __syncthreads();
    }
    int ex = sh[t] - s;
    if (t == 255) bsums[bsoff + lb] = sh[255];
    #pragma unroll
    for (int k = 0; k < 4; k++) { rowsts[base + k] = ex; ex += v[k]; }
}

__global__ __launch_bounds__(256) void k_scantop_all(int* __restrict__ bsums)
{
    __shared__ int sh[256];
    int b = blockIdx.x;
    int off0, nb;
    if (b == 0)      { off0 = 0;   nb = 196; }
    else if (b == 1) { off0 = 196; nb = 49; }
    else if (b == 2) { off0 = 245; nb = 13; }
    else if (b == 3) { off0 = 258; nb = 49; }
    else             { off0 = 307; nb = 13; }
    int t = threadIdx.x;
    int v = (t < nb) ? bsums[off0 + t] : 0;
    sh[t] = v;
    __syncthreads();
    for (int off = 1; off < 256; off <<= 1) {
        int x = 0;
        if (t >= off) x = sh[t - off];
        __syncthreads();
        if (t >= off) sh[t] += x;
        __syncthreads();
    }
    if (t < nb) bsums[off0 + t] = sh[t] - v; // exclusive
}

__global__ __launch_bounds__(256) void k_scanadd_all(
    int* __restrict__ rowsts, int* __restrict__ curss, const int* __restrict__ bsums,
    const int* __restrict__ degs, float* __restrict__ dinvs)
{
    int doff, bsoff, lb;
    seg_of_scanblk(blockIdx.x, doff, bsoff, lb);
    int t = threadIdx.x;
    int base = doff + lb * 1024 + t * 4;
    int add = bsums[bsoff + lb];
    bool dodinv = (doff <= 250880);
    #pragma unroll
    for (int k = 0; k < 4; k++) {
        int i = base + k;
        int r = rowsts[i] + add;
        rowsts[i] = r;
        curss[i] = r;
        if (dodinv) dinvs[i] = rsqrtf((float)degs[i] + 1.0f);
    }
}

__global__ void k_scatter_all(
    const int* __restrict__ s0, const int* __restrict__ d0,
    const int* __restrict__ s1, const int* __restrict__ d1,
    const int* __restrict__ s2, const int* __restrict__ d2,
    const int* __restrict__ p1, const int* __restrict__ p2,
    int* __restrict__ curss, int* __restrict__ elists)
{
    int gid = blockIdx.x * 256 + threadIdx.x;
    if (gid < 1600000) {
        int p = atomicAdd(&curss[d0[gid]], 1);
        elists[p] = s0[gid];
    } else if (gid < 2000000) {
        int i = gid - 1600000;
        int p = atomicAdd(&curss[200704 + d1[i]], 1);
        elists[1600000 + p] = s1[i];
    } else if (gid < 2100000) {
        int i = gid - 2000000;
        int p = atomicAdd(&curss[250880 + d2[i]], 1);
        elists[2000000 + p] = s2[i];
    } else if (gid < 2300000) {
        int i = gid - 2100000;
        int p = atomicAdd(&curss[264192 + p1[i]], 1);
        elists[2100000 + p] = i;
    } else if (gid < 2350000) {
        int i = gid - 2300000;
        int p = atomicAdd(&curss[314368 + p2[i]], 1);
        elists[2300000 + p] = i;
    }
}

// ---------------- GCN pieces -------------------------------------------------
// L0: h-row for node i is U[nodelist[i]] (U has only 50000 distinct rows)
__global__ __launch_bounds__(256) void k_gatherU(
    const float* __restrict__ U, const int* __restrict__ nl,
    const int* __restrict__ rowst, const int* __restrict__ elist,
    const float* __restrict__ dinv, const float* __restrict__ bias,
    float* __restrict__ out, int n)
{
    size_t gid = (size_t)blockIdx.x * 256 + threadIdx.x;
    int d = (int)(gid >> 5);
    if (d >= n) return;
    int l = (int)(gid & 31);
    const float4* Uv = (const float4*)U;
    float dd = dinv[d];
    float4 self = Uv[(size_t)nl[d] * 32 + l];
    float4 acc;
    acc.x = self.x * dd; acc.y = self.y * dd; acc.z = self.z * dd; acc.w = self.w * dd;
    int s0 = rowst[d], s1 = rowst[d + 1];
    for (int e = s0; e < s1; ++e) {
        int s = elist[e];
        float ds = dinv[s];
        float4 v = Uv[(size_t)nl[s] * 32 + l];
        acc.x = fmaf(v.x, ds, acc.x);
        acc.y = fmaf(v.y, ds, acc.y);
        acc.z = fmaf(v.z, ds, acc.z);
        acc.w = fmaf(v.w, ds, acc.w);
    }
    const float4 b = ((const float4*)bias)[l];
    float4 y;
    y.x = fmaxf(fmaf(acc.x, dd, b.x), 0.f);
    y.y = fmaxf(fmaf(acc.y, dd, b.y), 0.f);
    y.z = fmaxf(fmaf(acc.z, dd, b.z), 0.f);
    y.w = fmaxf(fmaf(acc.w, dd, b.w), 0.f);
    ((float4*)out)[(size_t)d * 32 + l] = y;
}

__global__ __launch_bounds__(256) void k_gather(
    const float* __restrict__ h, const int* __restrict__ rowst,
    const int* __restrict__ elist, const float* __restrict__ dinv,
    const float* __restrict__ bias, float* __restrict__ out, int n)
{
    size_t gid = (size_t)blockIdx.x * 256 + threadIdx.x;
    int d = (int)(gid >> 5);
    if (d >= n) return;
    int l = (int)(gid & 31);
    const float4* hv = (const float4*)h;
    float dd = dinv[d];
    float4 self = hv[(size_t)d * 32 + l];
    float4 acc;
    acc.x = self.x * dd; acc.y = self.y * dd; acc.z = self.z * dd; acc.w = self.w * dd;
    int s0 = rowst[d], s1 = rowst[d + 1];
    for (int e = s0; e < s1; ++e) {
        int s = elist[e];
        float ds = dinv[s];
        float4 v = hv[(size_t)s * 32 + l];
        acc.x = fmaf(v.x, ds, acc.x);
        acc.y = fmaf(v.y, ds, acc.y);
        acc.z = fmaf(v.z, ds, acc.z);
        acc.w = fmaf(v.w, ds, acc.w);
    }
    const float4 b = ((const float4*)bias)[l];
    float4 y;
    y.x = fmaxf(fmaf(acc.x, dd, b.x), 0.f);
    y.y = fmaxf(fmaf(acc.y, dd, b.y), 0.f);
    y.z = fmaxf(fmaf(acc.z, dd, b.z), 0.f);
    y.w = fmaxf(fmaf(acc.w, dd, b.w), 0.f);
    ((float4*)out)[(size_t)d * 32 + l] = y;
}

__global__ __launch_bounds__(256) void k_poolgather(
    const float* __restrict__ Y, const int* __restrict__ rowst,
    const int* __restrict__ elist, float* __restrict__ out, int np)
{
    size_t gid = (size_t)blockIdx.x * 256 + threadIdx.x;
    int p = (int)(gid >> 5);
    if (p >= np) return;
    int l = (int)(gid & 31);
    const float4* yv = (const float4*)Y;
    float4 acc = {0.f, 0.f, 0.f, 0.f};
    int s0 = rowst[p], s1 = rowst[p + 1];
    for (int e = s0; e < s1; ++e) {
        int i = elist[e];
        float4 v = yv[(size_t)i * 32 + l];
        acc.x += v.x; acc.y += v.y; acc.z += v.z; acc.w += v.w;
    }
    float4 y;
    y.x = fmaxf(acc.x, 0.f); y.y = fmaxf(acc.y, 0.f);
    y.z = fmaxf(acc.z, 0.f); y.w = fmaxf(acc.w, 0.f);
    ((float4*)out)[(size_t)p * 32 + l] = y;
}

__global__ __launch_bounds__(128) void k_bpool_all(
    const float* __restrict__ X1, const float* __restrict__ X2, const float* __restrict__ Y2,
    const int* __restrict__ b1, const int* __restrict__ b2, float* __restrict__ pl)
{
    int b = blockIdx.x;
    const float* src; const int* bidx; int coloff, n, r0;
    if (b < 391)      { src = X1; bidx = b1; coloff = 0;   n = 50000; r0 = b * 128; }
    else if (b < 489) { src = X2; bidx = b2; coloff = 128; n = 12500; r0 = (b - 391) * 128; }
    else              { src = Y2; bidx = b2; coloff = 256; n = 12500; r0 = (b - 489) * 128; }
    if (r0 >= n) return;
    int j = threadIdx.x;
    int r1 = min(r0 + 128, n);
    float acc = 0.f;
    int prev = bidx[r0];
    for (int r = r0; r < r1; ++r) {
        int bb = bidx[r];
        if (bb != prev) {
            unsafeAtomicAdd(&pl[(size_t)prev * 384 + coloff + j], acc);
            acc = 0.f; prev = bb;
        }
        acc += src[(size_t)r * 128 + j];
    }
    unsafeAtomicAdd(&pl[(size_t)prev * 384 + coloff + j], acc);
}

__global__ void k_mlp(const float* __restrict__ A, const float* __restrict__ W,
                      const float* __restrict__ b, float* __restrict__ out,
                      int K, int dorelu)
{
    __shared__ float as[384];
    int r = blockIdx.x, j = threadIdx.x;
    for (int i = j; i < K; i += 128) as[i] = A[(size_t)r * K + i];
    __syncthreads();
    float acc = b[j];
    for (int k = 0; k < K; k++) acc = fmaf(as[k], W[(size_t)k * 128 + j], acc);
    if (dorelu) acc = fmaxf(acc, 0.f);
    out[(size_t)r * 128 + j] = acc;
}

extern "C" void kernel_launch(void* const* d_in, const int* in_sizes, int n_in,
                              void* d_out, int out_size, void* d_ws, size_t ws_size,
                              hipStream_t stream)
{
    const float* x_raw  = (const float*)d_in[0];
    const float* W_des  = (const float*)d_in[1];
    const float* b_des  = (const float*)d_in[2];
    const float* W_twe  = (const float*)d_in[3];
    const float* b_twe  = (const float*)d_in[4];
    const float* W_num  = (const float*)d_in[5];
    const float* b_num  = (const float*)d_in[6];
    const float* W_cat  = (const float*)d_in[7];
    const float* b_cat  = (const float*)d_in[8];
    const float* W_in   = (const float*)d_in[9];
    const float* b_in   = (const float*)d_in[10];
    const float* prelua = (const float*)d_in[11];
    const float* W_conv = (const float*)d_in[12];
    const float* b_conv = (const float*)d_in[13];
    const float* Wc1    = (const float*)d_in[14];
    const float* bc1    = (const float*)d_in[15];
    const float* Wc2    = (const float*)d_in[16];
    const float* bc2    = (const float*)d_in[17];
    const int* nodelist = (const int*)d_in[18];
    const int* e0       = (const int*)d_in[19];
    const int* e1       = (const int*)d_in[20];
    const int* e2       = (const int*)d_in[21];
    const int* parent1  = (const int*)d_in[22];
    const int* parent2  = (const int*)d_in[23];
    const int* batch1   = (const int*)d_in[24];
    const int* batch2   = (const int*)d_in[25];

    // ---- workspace layout (~212 MB) ----
    float* WS  = (float*)d_ws;
    float* ENC = WS;                    // 50000*128; dead after U GEMM
    // CSR scratch aliases ENC (built after U GEMM):
    int*   DEGS   = (int*)d_ws;                // 327680
    int*   ROWSTS = DEGS + 327680;             // 327680
    int*   CURSS  = ROWSTS + 327680;           // 327680
    float* DINVS  = (float*)(CURSS + 327680);  // 264192
    int*   BSUMS  = (int*)(DINVS + 264192);    // 512
    int*   ELISTS = BSUMS + 512;               // 2,350,000 (14.4MB < 25.6MB)
    float* U  = WS + 6400000;           // 50000*128
    float* H  = WS + 12800000;          // 50000*128 (L1/L2 lin outputs)
    float* Y  = WS + 19200000;          // 200000*128
    float* X1 = WS + 44800000;          // 50000*128
    float* X2 = WS + 51200000;          // 12500*128
    float* PL = WS + 52800000;          // 128*384
    float* Z  = PL + 49152;             // 128*128

    hipMemsetAsync(PL, 0, (size_t)128 * 384 * 4, stream);

    // ---- encoder -> ENC; ENC = prelu(ENC@W_in+b) in-place; U = ENC@W_conv0 --
    k_enc3<<<(N_USERS + 63) / 64, 256, 0, stream>>>(
        x_raw, W_des, b_des, W_twe, b_twe, W_num, b_num, W_cat, b_cat, ENC);
    k_gemmT<1><<<(N_USERS + 31) / 32, 256, 0, stream>>>(
        ENC, W_in, b_in, prelua, ENC, N_USERS);
    k_gemmT<0><<<(N_USERS + 31) / 32, 256, 0, stream>>>(
        ENC, W_conv, nullptr, nullptr, U, N_USERS);

    // ---- fused CSR builds (+dinv); clobbers ENC (dead) ----
    hipMemsetAsync(DEGS, 0, (size_t)327680 * 4, stream);
    k_count_all<<<(2350000 + 255) / 256, 256, 0, stream>>>(
        e0 + EE0, e1 + EE1, e2 + EE2, parent1, parent2, DEGS);
    k_scan_all<<<320, 256, 0, stream>>>(DEGS, ROWSTS, BSUMS);
    k_scantop_all<<<5, 256, 0, stream>>>(BSUMS);
    k_scanadd_all<<<320, 256, 0, stream>>>(ROWSTS, CURSS, BSUMS, DEGS, DINVS);
    k_scatter_all<<<(2350000 + 255) / 256, 256, 0, stream>>>(
        e0, e0 + EE0, e1, e1 + EE1, e2, e2 + EE2, parent1, parent2, CURSS, ELISTS);

    // ---- layer 0: aggregate via U[nodelist[.]] + pool ----
    k_gatherU<<<(int)(((size_t)NN0 * 32 + 255) / 256), 256, 0, stream>>>(
        U, nodelist, ROWSTS, ELISTS, DINVS, b_conv, Y, NN0);
    k_poolgather<<<(int)(((size_t)NN1 * 32 + 255) / 256), 256, 0, stream>>>(
        Y, ROWSTS + 264192, ELISTS + 2100000, X1, NN1);

    // ---- layer 1 ----
    k_gemmT<0><<<(NN1 + 31) / 32, 256, 0, stream>>>(
        X1, W_conv + 16384, nullptr, nullptr, H, NN1);
    k_gather<<<(int)(((size_t)NN1 * 32 + 255) / 256), 256, 0, stream>>>(
        H, ROWSTS + 200704, ELISTS + 1600000, DINVS + 200704, b_conv + 128, Y, NN1);
    k_poolgather<<<(int)(((size_t)NN2 * 32 + 255) / 256), 256, 0, stream>>>(
        Y, ROWSTS + 314368, ELISTS + 2300000, X2, NN2);

    // ---- layer 2 ----
    k_gemmT<0><<<(NN2 + 31) / 32, 256, 0, stream>>>(
        X2, W_conv + 32768, nullptr, nullptr, H, NN2);
    k_gather<<<(int)(((size_t)NN2 * 32 + 255) / 256), 256, 0, stream>>>(
        H, ROWSTS + 250880, ELISTS + 2000000, DINVS + 250880, b_conv + 256, Y, NN2);

    // ---- batch pooling (fused, sorted keys) ----
    k_bpool_all<<<587, 128, 0, stream>>>(X1, X2, Y, batch1, batch2, PL);

    // ---- final MLP ----
    k_mlp<<<128, 128, 0, stream>>>(PL, Wc1, bc1, Z, 384, 1);
    k_mlp<<<128, 128, 0, stream>>>(Z, Wc2, bc2, (float*)d_out, 128, 0);
}

// Round 7
// 753.549 us; speedup vs baseline: 6.2032x; 1.1287x over previous
//
#include <hip/hip_runtime.h>

#define N_USERS 50000
#define NN0 200000
#define NN1 50000
#define NN2 12500
#define EE0 1600000
#define EE1 400000
#define EE2 100000

// Padded segment geometry for fused CSR builds (padded to 1024 multiples):
// seg:      0:e0        1:e1      2:e2      3:parent1  4:parent2
// deg off:  0           200704    250880    264192     314368   (total 327680)
// scan blk: 196         49        13        49         13       (cum 196,245,258,307,320)
// bsum off: 0           196       245       258        307
// el off:   0           1600000   2000000   2100000    2300000
// edges:    1600000     400000    100000    200000     50000    (total 2350000)

// ---------------- encoder: h128[r] = leaky([d|t|n|c]) -------------------------
__global__ __launch_bounds__(256) void k_enc3(
    const float* __restrict__ xr,
    const float* __restrict__ Wd, const float* __restrict__ bd,
    const float* __restrict__ Wt, const float* __restrict__ bt,
    const float* __restrict__ Wn, const float* __restrict__ bn,
    const float* __restrict__ Wc, const float* __restrict__ bc,
    float* __restrict__ h128)
{
    __shared__ float XsD[32][68];  // [k][row] des chunk (transposed)
    __shared__ float XsT[32][68];  // [k][row] tweet chunk
    __shared__ float Ws[32][68];   // [k][col 0..63] = [Wd|Wt]
    __shared__ float xnc[64][8];   // num(6)+cat(2) inputs
    __shared__ float Wl[8][64];    // light weights, zero-padded per plane

    int t = threadIdx.x;
    int cg = t & 15, rg = t >> 4;  // cols 4cg..+3, rows 4rg..+3
    int base = blockIdx.x * 64;

    if (t < 64) {
        int row = base + t;
        if (row < N_USERS) {
            const float* xp = xr + (size_t)row * 1544;
            float4 a = *(const float4*)xp;
            float2 b2 = *(const float2*)(xp + 4);
            float2 c2 = *(const float2*)(xp + 774);
            xnc[t][0] = a.x; xnc[t][1] = a.y; xnc[t][2] = a.z; xnc[t][3] = a.w;
            xnc[t][4] = b2.x; xnc[t][5] = b2.y; xnc[t][6] = c2.x; xnc[t][7] = c2.y;
        } else {
            #pragma unroll
            for (int k = 0; k < 8; k++) xnc[t][k] = 0.f;
        }
    } else if (t >= 192) {
        int l = t - 192;
        #pragma unroll
        for (int k = 0; k < 8; k++) {
            float w = 0.f;
            if (l < 32) { if (k < 6) w = Wn[k * 32 + l]; }
            else        { if (k >= 6) w = Wc[(k - 6) * 32 + (l - 32)]; }
            Wl[k][l] = w;
        }
    }

    float acc[4][4];
    #pragma unroll
    for (int r = 0; r < 4; r++)
        #pragma unroll
        for (int c = 0; c < 4; c++) acc[r][c] = 0.f;

    for (int kc = 0; kc < 768; kc += 32) {
        __syncthreads();
        #pragma unroll
        for (int h = 0; h < 2; h++) {
            int fi = t * 2 + h;
            int row = fi >> 3, q = fi & 7;
            int grow = base + row;
            float4 vd = {0.f, 0.f, 0.f, 0.f};
            float2 va = {0.f, 0.f}, vb = {0.f, 0.f};
            if (grow < N_USERS) {
                const float* xp = xr + (size_t)grow * 1544 + kc + q * 4;
                vd = *(const float4*)(xp + 776);  // 16B aligned
                va = *(const float2*)(xp + 6);    // 8B aligned
                vb = *(const float2*)(xp + 8);
            }
            int k0 = q * 4;
            XsD[k0 + 0][row] = vd.x; XsD[k0 + 1][row] = vd.y;
            XsD[k0 + 2][row] = vd.z; XsD[k0 + 3][row] = vd.w;
            XsT[k0 + 0][row] = va.x; XsT[k0 + 1][row] = va.y;
            XsT[k0 + 2][row] = vb.x; XsT[k0 + 3][row] = vb.y;
        }
        #pragma unroll
        for (int h = 0; h < 2; h++) {
            int fi = t + h * 256;
            int k = fi >> 4, c4 = (fi & 15) * 4;
            float4 w = (c4 < 32) ? *(const float4*)(Wd + (size_t)(kc + k) * 32 + c4)
                                 : *(const float4*)(Wt + (size_t)(kc + k) * 32 + (c4 - 32));
            *(float4*)&Ws[k][c4] = w;
        }
        __syncthreads();

        const float* Xp = (cg < 8) ? &XsD[0][0] : &XsT[0][0];
        #pragma unroll 8
        for (int k = 0; k < 32; k++) {
            float4 xv = *(const float4*)(Xp + k * 68 + rg * 4);
            float4 wv = *(const float4*)&Ws[k][cg * 4];
            acc[0][0] = fmaf(xv.x, wv.x, acc[0][0]);
            acc[0][1] = fmaf(xv.x, wv.y, acc[0][1]);
            acc[0][2] = fmaf(xv.x, wv.z, acc[0][2]);
            acc[0][3] = fmaf(xv.x, wv.w, acc[0][3]);
            acc[1][0] = fmaf(xv.y, wv.x, acc[1][0]);
            acc[1][1] = fmaf(xv.y, wv.y, acc[1][1]);
            acc[1][2] = fmaf(xv.y, wv.z, acc[1][2]);
            acc[1][3] = fmaf(xv.y, wv.w, acc[1][3]);
            acc[2][0] = fmaf(xv.z, wv.x, acc[2][0]);
            acc[2][1] = fmaf(xv.z, wv.y, acc[2][1]);
            acc[2][2] = fmaf(xv.z, wv.z, acc[2][2]);
            acc[2][3] = fmaf(xv.z, wv.w, acc[2][3]);
            acc[3][0] = fmaf(xv.w, wv.x, acc[3][0]);
            acc[3][1] = fmaf(xv.w, wv.y, acc[3][1]);
            acc[3][2] = fmaf(xv.w, wv.z, acc[3][2]);
            acc[3][3] = fmaf(xv.w, wv.w, acc[3][3]);
        }
    }

    float bh[4], bl[4], wlv[8][4];
    #pragma unroll
    for (int c = 0; c < 4; c++) {
        int j = cg * 4 + c;
        bh[c] = (j < 32) ? bd[j] : bt[j - 32];
        bl[c] = (j < 32) ? bn[j] : bc[j - 32];
        #pragma unroll
        for (int k = 0; k < 8; k++) wlv[k][c] = Wl[k][j];
    }
    #pragma unroll
    for (int r = 0; r < 4; r++) {
        int lr = rg * 4 + r;
        int row = base + lr;
        if (row >= N_USERS) break;
        float4 hv;
        float* ph = &hv.x;
        #pragma unroll
        for (int c = 0; c < 4; c++) {
            float v = acc[r][c] + bh[c];
            ph[c] = v > 0.f ? v : 0.01f * v;
        }
        *(float4*)(h128 + (size_t)row * 128 + cg * 4) = hv;
        float4 lv;
        float* pl = &lv.x;
        #pragma unroll
        for (int c = 0; c < 4; c++) {
            float v = bl[c];
            #pragma unroll
            for (int k = 0; k < 8; k++) v = fmaf(xnc[lr][k], wlv[k][c], v);
            pl[c] = v > 0.f ? v : 0.01f * v;
        }
        *(float4*)(h128 + (size_t)row * 128 + 64 + cg * 4) = lv;
    }
}

// ---------------- [n,128] @ [128,128] GEMM, 4x4 register tile ----------------
template<int EPI> // 0: plain, 1: prelu(x+b)
__global__ __launch_bounds__(256) void k_gemmT(
    const float* X, const float* __restrict__ W, const float* __restrict__ bias,
    const float* __restrict__ pa, float* OUT, int n)
{
    __shared__ float Xs[32][132];  // [row][k] whole K=128
    __shared__ float Ws[32][132];  // [k][col] chunk
    int t = threadIdx.x;
    int cg = t & 31, rg = t >> 5;  // cols 4cg..+3, rows 4rg..+3
    int base = blockIdx.x * 32;

    #pragma unroll
    for (int h = 0; h < 4; h++) {
        int fi = t + h * 256;
        int row = fi >> 5, q = fi & 31;
        float4 v = {0.f, 0.f, 0.f, 0.f};
        if (base + row < n) v = *(const float4*)(X + (size_t)(base + row) * 128 + q * 4);
        *(float4*)&Xs[row][q * 4] = v;
    }

    float acc[4][4];
    #pragma unroll
    for (int r = 0; r < 4; r++)
        #pragma unroll
        for (int c = 0; c < 4; c++) acc[r][c] = 0.f;

    for (int kc = 0; kc < 128; kc += 32) {
        __syncthreads();
        // stage W chunk: 32 k-rows x 128 cols = 1024 float4 = 4 x 256 threads
        #pragma unroll
        for (int h = 0; h < 4; h++) {
            int fi = t + h * 256;
            int k = fi >> 5, q = fi & 31;
            *(float4*)&Ws[k][q * 4] = *(const float4*)(W + (size_t)(kc + k) * 128 + q * 4);
        }
        __syncthreads();
        #pragma unroll
        for (int k4 = 0; k4 < 8; k4++) {
            int k = k4 * 4;
            float4 w0 = *(const float4*)&Ws[k + 0][cg * 4];
            float4 w1 = *(const float4*)&Ws[k + 1][cg * 4];
            float4 w2 = *(const float4*)&Ws[k + 2][cg * 4];
            float4 w3 = *(const float4*)&Ws[k + 3][cg * 4];
            #pragma unroll
            for (int r = 0; r < 4; r++) {
                float4 xv = *(const float4*)&Xs[rg * 4 + r][kc + k];
                acc[r][0] = fmaf(xv.w, w3.x, fmaf(xv.z, w2.x, fmaf(xv.y, w1.x, fmaf(xv.x, w0.x, acc[r][0]))));
                acc[r][1] = fmaf(xv.w, w3.y, fmaf(xv.z, w2.y, fmaf(xv.y, w1.y, fmaf(xv.x, w0.y, acc[r][1]))));
                acc[r][2] = fmaf(xv.w, w3.z, fmaf(xv.z, w2.z, fmaf(xv.y, w1.z, fmaf(xv.x, w0.z, acc[r][2]))));
                acc[r][3] = fmaf(xv.w, w3.w, fmaf(xv.z, w2.w, fmaf(xv.y, w1.w, fmaf(xv.x, w0.w, acc[r][3]))));
            }
        }
    }

    float4 bv = {0.f, 0.f, 0.f, 0.f}, pv = {0.f, 0.f, 0.f, 0.f};
    if (EPI == 1) { bv = *(const float4*)(bias + cg * 4); pv = *(const float4*)(pa + cg * 4); }
    #pragma unroll
    for (int r = 0; r < 4; r++) {
        int row = base + rg * 4 + r;
        if (row >= n) break;
        float4 v;
        if (EPI == 1) {
            v.x = acc[r][0] + bv.x; v.x = v.x > 0.f ? v.x : pv.x * v.x;
            v.y = acc[r][1] + bv.y; v.y = v.y > 0.f ? v.y : pv.y * v.y;
            v.z = acc[r][2] + bv.z; v.z = v.z > 0.f ? v.z : pv.z * v.z;
            v.w = acc[r][3] + bv.w; v.w = v.w > 0.f ? v.w : pv.w * v.w;
        } else {
            v.x = acc[r][0]; v.y = acc[r][1]; v.z = acc[r][2]; v.w = acc[r][3];
        }
        *(float4*)(OUT + (size_t)row * 128 + cg * 4) = v;
    }
}

// ---------------- fused CSR build over 5 segments ----------------------------
__device__ __forceinline__ void seg_of_scanblk(int b, int& doff, int& bsoff, int& lb) {
    if (b < 196)      { doff = 0;      bsoff = 0;   lb = b; }
    else if (b < 245) { doff = 200704; bsoff = 196; lb = b - 196; }
    else if (b < 258) { doff = 250880; bsoff = 245; lb = b - 245; }
    else if (b < 307) { doff = 264192; bsoff = 258; lb = b - 258; }
    else              { doff = 314368; bsoff = 307; lb = b - 307; }
}

// count + record rank (atomicAdd return) — 4 edges per thread for ILP
__global__ __launch_bounds__(256) void k_count_all(
    const int* __restrict__ d0, const int* __restrict__ d1, const int* __restrict__ d2,
    const int* __restrict__ p1, const int* __restrict__ p2,
    int* __restrict__ degs, int* __restrict__ ranks)
{
    int t0 = blockIdx.x * 256 + threadIdx.x;
    if (t0 >= 587500) return;
    #pragma unroll
    for (int k = 0; k < 4; k++) {
        int gid = t0 + k * 587500;
        int idx;
        if (gid < 1600000)      idx = d0[gid];
        else if (gid < 2000000) idx = 200704 + d1[gid - 1600000];
        else if (gid < 2100000) idx = 250880 + d2[gid - 2000000];
        else if (gid < 2300000) idx = 264192 + p1[gid - 2100000];
        else                    idx = 314368 + p2[gid - 2300000];
        ranks[gid] = atomicAdd(&degs[idx], 1);
    }
}

__global__ __launch_bounds__(256) void k_scan_all(
    const int* __restrict__ degs, int* __restrict__ rowsts, int* __restrict__ bsums)
{
    __shared__ int sh[256];
    int doff, bsoff, lb;
    seg_of_scanblk(blockIdx.x, doff, bsoff, lb);
    int t = threadIdx.x;
    int base = doff + lb * 1024 + t * 4;
    int v[4], s = 0;
    #pragma unroll
    for (int k = 0; k < 4; k++) { v[k] = degs[base + k]; s += v[k]; }
    sh[t] = s;
    __syncthreads();
    for (int off = 1; off < 256; off <<= 1) {
        int x = 0;
        if (t >= off) x = sh[t - off];
        __syncthreads();
        if (t >= off) sh[t] += x;
        __syncthreads();
    }
    int ex = sh[t] - s;
    if (t == 255) bsums[bsoff + lb] = sh[255];
    #pragma unroll
    for (int k = 0; k < 4; k++) { rowsts[base + k] = ex; ex += v[k]; }
}

__global__ __launch_bounds__(256) void k_scantop_all(int* __restrict__ bsums)
{
    __shared__ int sh[256];
    int b = blockIdx.x;
    int off0, nb;
    if (b == 0)      { off0 = 0;   nb = 196; }
    else if (b == 1) { off0 = 196; nb = 49; }
    else if (b == 2) { off0 = 245; nb = 13; }
    else if (b == 3) { off0 = 258; nb = 49; }
    else             { off0 = 307; nb = 13; }
    int t = threadIdx.x;
    int v = (t < nb) ? bsums[off0 + t] : 0;
    sh[t] = v;
    __syncthreads();
    for (int off = 1; off < 256; off <<= 1) {
        int x = 0;
        if (t >= off) x = sh[t - off];
        __syncthreads();
        if (t >= off) sh[t] += x;
        __syncthreads();
    }
    if (t < nb) bsums[off0 + t] = sh[t] - v; // exclusive
}

// add block offsets + compute dinv for segs 0-2
__global__ __launch_bounds__(256) void k_scanadd_all(
    int* __restrict__ rowsts, const int* __restrict__ bsums,
    const int* __restrict__ degs, float* __restrict__ dinvs)
{
    int doff, bsoff, lb;
    seg_of_scanblk(blockIdx.x, doff, bsoff, lb);
    int t = threadIdx.x;
    int base = doff + lb * 1024 + t * 4;
    int add = bsums[bsoff + lb];
    bool dodinv = (doff <= 250880);
    #pragma unroll
    for (int k = 0; k < 4; k++) {
        int i = base + k;
        rowsts[i] += add;
        if (dodinv) dinvs[i] = rsqrtf((float)degs[i] + 1.0f);
    }
}

// atomic-free scatter: p = rowsts[key] + rank[e]
__global__ __launch_bounds__(256) void k_scatter_all(
    const int* __restrict__ s0, const int* __restrict__ d0,
    const int* __restrict__ s1, const int* __restrict__ d1,
    const int* __restrict__ s2, const int* __restrict__ d2,
    const int* __restrict__ p1, const int* __restrict__ p2,
    const int* __restrict__ rowsts, const int* __restrict__ ranks,
    int* __restrict__ elists)
{
    int t0 = blockIdx.x * 256 + threadIdx.x;
    if (t0 >= 587500) return;
    #pragma unroll
    for (int k = 0; k < 4; k++) {
        int gid = t0 + k * 587500;
        int idx, val, eloff;
        if (gid < 1600000)      { idx = d0[gid];                    val = s0[gid];           eloff = 0; }
        else if (gid < 2000000) { int i = gid - 1600000; idx = 200704 + d1[i]; val = s1[i]; eloff = 1600000; }
        else if (gid < 2100000) { int i = gid - 2000000; idx = 250880 + d2[i]; val = s2[i]; eloff = 2000000; }
        else if (gid < 2300000) { int i = gid - 2100000; idx = 264192 + p1[i]; val = i;     eloff = 2100000; }
        else                    { int i = gid - 2300000; idx = 314368 + p2[i]; val = i;     eloff = 2300000; }
        int p = rowsts[idx] + ranks[gid];
        elists[eloff + p] = val;
    }
}

// ---------------- GCN pieces -------------------------------------------------
// L0: h-row for node i is U[nodelist[i]] (U has only 50000 distinct rows)
__global__ __launch_bounds__(256) void k_gatherU(
    const float* __restrict__ U, const int* __restrict__ nl,
    const int* __restrict__ rowst, const int* __restrict__ elist,
    const float* __restrict__ dinv, const float* __restrict__ bias,
    float* __restrict__ out, int n)
{
    size_t gid = (size_t)blockIdx.x * 256 + threadIdx.x;
    int d = (int)(gid >> 5);
    if (d >= n) return;
    int l = (int)(gid & 31);
    const float4* Uv = (const float4*)U;
    float dd = dinv[d];
    float4 self = Uv[(size_t)nl[d] * 32 + l];
    float4 acc;
    acc.x = self.x * dd; acc.y = self.y * dd; acc.z = self.z * dd; acc.w = self.w * dd;
    int s0 = rowst[d], s1 = rowst[d + 1];
    for (int e = s0; e < s1; ++e) {
        int s = elist[e];
        float ds = dinv[s];
        float4 v = Uv[(size_t)nl[s] * 32 + l];
        acc.x = fmaf(v.x, ds, acc.x);
        acc.y = fmaf(v.y, ds, acc.y);
        acc.z = fmaf(v.z, ds, acc.z);
        acc.w = fmaf(v.w, ds, acc.w);
    }
    const float4 b = ((const float4*)bias)[l];
    float4 y;
    y.x = fmaxf(fmaf(acc.x, dd, b.x), 0.f);
    y.y = fmaxf(fmaf(acc.y, dd, b.y), 0.f);
    y.z = fmaxf(fmaf(acc.z, dd, b.z), 0.f);
    y.w = fmaxf(fmaf(acc.w, dd, b.w), 0.f);
    ((float4*)out)[(size_t)d * 32 + l] = y;
}

__global__ __launch_bounds__(256) void k_gather(
    const float* __restrict__ h, const int* __restrict__ rowst,
    const int* __restrict__ elist, const float* __restrict__ dinv,
    const float* __restrict__ bias, float* __restrict__ out, int n)
{
    size_t gid = (size_t)blockIdx.x * 256 + threadIdx.x;
    int d = (int)(gid >> 5);
    if (d >= n) return;
    int l = (int)(gid & 31);
    const float4* hv = (const float4*)h;
    float dd = dinv[d];
    float4 self = hv[(size_t)d * 32 + l];
    float4 acc;
    acc.x = self.x * dd; acc.y = self.y * dd; acc.z = self.z * dd; acc.w = self.w * dd;
    int s0 = rowst[d], s1 = rowst[d + 1];
    for (int e = s0; e < s1; ++e) {
        int s = elist[e];
        float ds = dinv[s];
        float4 v = hv[(size_t)s * 32 + l];
        acc.x = fmaf(v.x, ds, acc.x);
        acc.y = fmaf(v.y, ds, acc.y);
        acc.z = fmaf(v.z, ds, acc.z);
        acc.w = fmaf(v.w, ds, acc.w);
    }
    const float4 b = ((const float4*)bias)[l];
    float4 y;
    y.x = fmaxf(fmaf(acc.x, dd, b.x), 0.f);
    y.y = fmaxf(fmaf(acc.y, dd, b.y), 0.f);
    y.z = fmaxf(fmaf(acc.z, dd, b.z), 0.f);
    y.w = fmaxf(fmaf(acc.w, dd, b.w), 0.f);
    ((float4*)out)[(size_t)d * 32 + l] = y;
}

__global__ __launch_bounds__(256) void k_poolgather(
    const float* __restrict__ Y, const int* __restrict__ rowst,
    const int* __restrict__ elist, float* __restrict__ out, int np)
{
    size_t gid = (size_t)blockIdx.x * 256 + threadIdx.x;
    int p = (int)(gid >> 5);
    if (p >= np) return;
    int l = (int)(gid & 31);
    const float4* yv = (const float4*)Y;
    float4 acc = {0.f, 0.f, 0.f, 0.f};
    int s0 = rowst[p], s1 = rowst[p + 1];
    for (int e = s0; e < s1; ++e) {
        int i = elist[e];
        float4 v = yv[(size_t)i * 32 + l];
        acc.x += v.x; acc.y += v.y; acc.z += v.z; acc.w += v.w;
    }
    float4 y;
    y.x = fmaxf(acc.x, 0.f); y.y = fmaxf(acc.y, 0.f);
    y.z = fmaxf(acc.z, 0.f); y.w = fmaxf(acc.w, 0.f);
    ((float4*)out)[(size_t)p * 32 + l] = y;
}

__global__ __launch_bounds__(128) void k_bpool_all(
    const float* __restrict__ X1, const float* __restrict__ X2, const float* __restrict__ Y2,
    const int* __restrict__ b1, const int* __restrict__ b2, float* __restrict__ pl)
{
    int b = blockIdx.x;
    const float* src; const int* bidx; int coloff, n, r0;
    if (b < 391)      { src = X1; bidx = b1; coloff = 0;   n = 50000; r0 = b * 128; }
    else if (b < 489) { src = X2; bidx = b2; coloff = 128; n = 12500; r0 = (b - 391) * 128; }
    else              { src = Y2; bidx = b2; coloff = 256; n = 12500; r0 = (b - 489) * 128; }
    if (r0 >= n) return;
    int j = threadIdx.x;
    int r1 = min(r0 + 128, n);
    float acc = 0.f;
    int prev = bidx[r0];
    for (int r = r0; r < r1; ++r) {
        int bb = bidx[r];
        if (bb != prev) {
            unsafeAtomicAdd(&pl[(size_t)prev * 384 + coloff + j], acc);
            acc = 0.f; prev = bb;
        }
        acc += src[(size_t)r * 128 + j];
    }
    unsafeAtomicAdd(&pl[(size_t)prev * 384 + coloff + j], acc);
}

__global__ void k_mlp(const float* __restrict__ A, const float* __restrict__ W,
                      const float* __restrict__ b, float* __restrict__ out,
                      int K, int dorelu)
{
    __shared__ float as[384];
    int r = blockIdx.x, j = threadIdx.x;
    for (int i = j; i < K; i += 128) as[i] = A[(size_t)r * K + i];
    __syncthreads();
    float acc = b[j];
    for (int k = 0; k < K; k++) acc = fmaf(as[k], W[(size_t)k * 128 + j], acc);
    if (dorelu) acc = fmaxf(acc, 0.f);
    out[(size_t)r * 128 + j] = acc;
}

extern "C" void kernel_launch(void* const* d_in, const int* in_sizes, int n_in,
                              void* d_out, int out_size, void* d_ws, size_t ws_size,
                              hipStream_t stream)
{
    const float* x_raw  = (const float*)d_in[0];
    const float* W_des  = (const float*)d_in[1];
    const float* b_des  = (const float*)d_in[2];
    const float* W_twe  = (const float*)d_in[3];
    const float* b_twe  = (const float*)d_in[4];
    const float* W_num  = (const float*)d_in[5];
    const float* b_num  = (const float*)d_in[6];
    const float* W_cat  = (const float*)d_in[7];
    const float* b_cat  = (const float*)d_in[8];
    const float* W_in   = (const float*)d_in[9];
    const float* b_in   = (const float*)d_in[10];
    const float* prelua = (const float*)d_in[11];
    const float* W_conv = (const float*)d_in[12];
    const float* b_conv = (const float*)d_in[13];
    const float* Wc1    = (const float*)d_in[14];
    const float* bc1    = (const float*)d_in[15];
    const float* Wc2    = (const float*)d_in[16];
    const float* bc2    = (const float*)d_in[17];
    const int* nodelist = (const int*)d_in[18];
    const int* e0       = (const int*)d_in[19];
    const int* e1       = (const int*)d_in[20];
    const int* e2       = (const int*)d_in[21];
    const int* parent1  = (const int*)d_in[22];
    const int* parent2  = (const int*)d_in[23];
    const int* batch1   = (const int*)d_in[24];
    const int* batch2   = (const int*)d_in[25];

    // ---- workspace layout ----
    float* WS  = (float*)d_ws;
    float* ENC = WS;                    // 50000*128 = 6.4M floats; dead after U GEMM
    // CSR scratch aliases ENC (built after U GEMM): 22.5 MB < 25.6 MB
    int*   DEGS   = (int*)d_ws;                 // 327680
    int*   ROWSTS = DEGS + 327680;              // 327680
    float* DINVS  = (float*)(ROWSTS + 327680);  // 264192
    int*   BSUMS  = (int*)(DINVS + 264192);     // 512
    int*   RANKS  = BSUMS + 512;                // 2350000
    int*   ELISTS = RANKS + 2350000;            // 2350000
    float* U  = WS + 6400000;           // 50000*128
    float* H  = WS + 12800000;          // 50000*128 (L1/L2 lin outputs)
    float* Y  = WS + 19200000;          // 200000*128
    float* X1 = WS + 44800000;          // 50000*128
    float* X2 = WS + 51200000;          // 12500*128
    float* PL = WS + 52800000;          // 128*384
    float* Z  = PL + 49152;             // 128*128

    hipMemsetAsync(PL, 0, (size_t)128 * 384 * 4, stream);

    // ---- encoder -> ENC; ENC = prelu(ENC@W_in+b) in-place; U = ENC@W_conv0 --
    k_enc3<<<(N_USERS + 63) / 64, 256, 0, stream>>>(
        x_raw, W_des, b_des, W_twe, b_twe, W_num, b_num, W_cat, b_cat, ENC);
    k_gemmT<1><<<(N_USERS + 31) / 32, 256, 0, stream>>>(
        ENC, W_in, b_in, prelua, ENC, N_USERS);
    k_gemmT<0><<<(N_USERS + 31) / 32, 256, 0, stream>>>(
        ENC, W_conv, nullptr, nullptr, U, N_USERS);

    // ---- fused CSR builds (+dinv); clobbers ENC (dead) ----
    hipMemsetAsync(DEGS, 0, (size_t)327680 * 4, stream);
    k_count_all<<<(587500 + 255) / 256, 256, 0, stream>>>(
        e0 + EE0, e1 + EE1, e2 + EE2, parent1, parent2, DEGS, RANKS);
    k_scan_all<<<320, 256, 0, stream>>>(DEGS, ROWSTS, BSUMS);
    k_scantop_all<<<5, 256, 0, stream>>>(BSUMS);
    k_scanadd_all<<<320, 256, 0, stream>>>(ROWSTS, BSUMS, DEGS, DINVS);
    k_scatter_all<<<(587500 + 255) / 256, 256, 0, stream>>>(
        e0, e0 + EE0, e1, e1 + EE1, e2, e2 + EE2, parent1, parent2,
        ROWSTS, RANKS, ELISTS);

    // ---- layer 0: aggregate via U[nodelist[.]] + pool ----
    k_gatherU<<<(int)(((size_t)NN0 * 32 + 255) / 256), 256, 0, stream>>>(
        U, nodelist, ROWSTS, ELISTS, DINVS, b_conv, Y, NN0);
    k_poolgather<<<(int)(((size_t)NN1 * 32 + 255) / 256), 256, 0, stream>>>(
        Y, ROWSTS + 264192, ELISTS + 2100000, X1, NN1);

    // ---- layer 1 ----
    k_gemmT<0><<<(NN1 + 31) / 32, 256, 0, stream>>>(
        X1, W_conv + 16384, nullptr, nullptr, H, NN1);
    k_gather<<<(int)(((size_t)NN1 * 32 + 255) / 256), 256, 0, stream>>>(
        H, ROWSTS + 200704, ELISTS + 1600000, DINVS + 200704, b_conv + 128, Y, NN1);
    k_poolgather<<<(int)(((size_t)NN2 * 32 + 255) / 256), 256, 0, stream>>>(
        Y, ROWSTS + 314368, ELISTS + 2300000, X2, NN2);

    // ---- layer 2 ----
    k_gemmT<0><<<(NN2 + 31) / 32, 256, 0, stream>>>(
        X2, W_conv + 32768, nullptr, nullptr, H, NN2);
    k_gather<<<(int)(((size_t)NN2 * 32 + 255) / 256), 256, 0, stream>>>(
        H, ROWSTS + 250880, ELISTS + 2000000, DINVS + 250880, b_conv + 256, Y, NN2);

    // ---- batch pooling (fused, sorted keys) ----
    k_bpool_all<<<587, 128, 0, stream>>>(X1, X2, Y, batch1, batch2, PL);

    // ---- final MLP ----
    k_mlp<<<128, 128, 0, stream>>>(PL, Wc1, bc1, Z, 384, 1);
    k_mlp<<<128, 128, 0, stream>>>(Z, Wc2, bc2, (float*)d_out, 128, 0);
}